// Round 7
// baseline (246.875 us; speedup 1.0000x reference)
//
#include <hip/hip_runtime.h>
#include <hip/hip_cooperative_groups.h>
#include <math.h>

namespace cg = cooperative_groups;

#define EMBED 512
#define HEADS 8
#define HDIM 64
#define SLEN 2048
#define BATCH 2
#define HALFW 128
#define NCHUNK 32
#define INV_SCALE 0.044194173824159216f  // 1/sqrt(512)

typedef short bf16x8 __attribute__((ext_vector_type(8)));
typedef short s16x4  __attribute__((ext_vector_type(4)));
typedef float f32x4  __attribute__((ext_vector_type(4)));

#define MFMA16(a, b, c) __builtin_amdgcn_mfma_f32_16x16x32_bf16(a, b, c, 0, 0, 0)

__device__ __forceinline__ short f2bf(float x) {
    union { float f; unsigned u; } v; v.f = x;
    unsigned r = v.u + 0x7FFFu + ((v.u >> 16) & 1u);  // RNE
    return (short)(r >> 16);
}

// Blocked-frag layout for a 64x64 bf16 tile (global AND LDS), XOR-swizzled:
// 16B fragment (row, seg) at short index ((seg*64) + (row^seg)) * 8.
// Frag reads & staging writes bank-conflict-free (R2-R6: SQ_LDS_BANK_CONFLICT=0).
__device__ __forceinline__ int lidx(int row, int seg) {
    return (((seg << 6) + (row ^ seg)) << 3);
}

// async global->LDS, 16B per lane. dest: wave-uniform base, HW adds lane*16.
__device__ __forceinline__ void gll16(const short* g, short* l) {
    __builtin_amdgcn_global_load_lds(
        (const __attribute__((address_space(1))) unsigned int*)g,
        (__attribute__((address_space(3))) unsigned int*)l, 16, 0, 0);
}

// identity-copy two 8KB frag tiles (layout preserved: dest off == src off)
__device__ __forceinline__ void stage_chunk(const short* s0, const short* s1,
                                            short* d0, short* d1, int t) {
    int off = t * 8;              // shorts
    int wb  = (t >> 6) * 512;     // wave-uniform LDS base (shorts)
    gll16(s0 + off,        d0 + wb);
    gll16(s0 + 2048 + off, d0 + 2048 + wb);
    gll16(s1 + off,        d1 + wb);
    gll16(s1 + 2048 + off, d1 + 2048 + wb);
}

struct PrepassS {
    float q0s[64];
    float wls[64];
    int   m_s[64];
    float vbuf[64][68];
    float red[4][64];
    float redv[4][64];
};
struct WindowedS {
    short k_s[2][4096];
    short v_s[2][4096];
    short wT_s[4][16][72];
    float rsum[64];
    float vred[4][64];
    float gred[4][64];
    float nv;
    float gd;
};
struct FcS {
    short a_s[2][4096];
    short b_s[2][4096];
};
constexpr size_t SMEM_MAX =
    sizeof(WindowedS) > sizeof(FcS)
        ? (sizeof(WindowedS) > sizeof(PrepassS) ? sizeof(WindowedS) : sizeof(PrepassS))
        : (sizeof(FcS) > sizeof(PrepassS) ? sizeof(FcS) : sizeof(PrepassS));

// ---------------------------------------------------------------------------
// Single cooperative kernel: 512 blocks x 256 threads, 3 phases, 2 grid syncs.
//   phase 1 (prepass):  (c,h,b)  Q/K/V -> frag bf16 (K mask-zeroed, V^T);
//                       row-0 attn partials + vsum/nvalid partials (unique
//                       writer per slot, no atomics); c<4 also convert fc_w.
//   phase 2 (windowed): (tile,h,b) banded attn, writes Abf frag tiles;
//                       reduces phase-1 partials in LDS; tile 0 = row 0.
//   phase 3 (fc):       (bm,nb) GEMM Abf x Wbf + bias -> out.
// ---------------------------------------------------------------------------
__global__ __launch_bounds__(256, 2) void fused_all(
    const float* __restrict__ q, const float* __restrict__ k,
    const float* __restrict__ v, const int* __restrict__ mask,
    const float* __restrict__ fcw, const float* __restrict__ bias,
    short* __restrict__ Qbf, short* __restrict__ Kbf, short* __restrict__ Vbf,
    short* __restrict__ Wbf, short* __restrict__ Abf,
    float* __restrict__ vsum_part, float* __restrict__ gnum_part,
    float* __restrict__ gden_part, float* __restrict__ nval_part,
    float* __restrict__ out)
{
    __shared__ __align__(16) char smem_raw[SMEM_MAX];
    cg::grid_group grid = cg::this_grid();
    int bid = blockIdx.x;
    int t = threadIdx.x, w = t >> 6, l = t & 63;
    int lg = l >> 4, lr = l & 15;

    // ===================== phase 1: prepass =====================
    {
        int c = bid & 31, h = (bid >> 5) & 7, b = bid >> 8;
        int j0 = c * 64;
        PrepassS& S = *reinterpret_cast<PrepassS*>(smem_raw);

        if (t < 64) {
            S.q0s[t] = q[(size_t)b * SLEN * EMBED + h * HDIM + t];
            S.m_s[t] = mask[b * SLEN + j0 + t];
        }
        __syncthreads();

        size_t fragbase = ((size_t)(b * HEADS + h) * NCHUNK + c) * 4096;

        // Q tile -> Qbf frags
        #pragma unroll
        for (int p = 0; p < 4; ++p) {
            int idx = p * 256 + t, row = idx >> 4, kg = idx & 15;
            float4 f = *(const float4*)(q + ((size_t)b * SLEN + j0 + row) * EMBED + h * HDIM + kg * 4);
            s16x4 o;
            o[0] = f2bf(f.x); o[1] = f2bf(f.y); o[2] = f2bf(f.z); o[3] = f2bf(f.w);
            *(s16x4*)&Qbf[fragbase + lidx(row, kg >> 1) + (kg & 1) * 4] = o;
        }

        // K chunk -> Kbf frags (masked rows zeroed) + row-0 dot
        #pragma unroll
        for (int p = 0; p < 4; ++p) {
            int idx = p * 256 + t, row = idx >> 4, kg = idx & 15;
            float4 f = *(const float4*)(k + ((size_t)b * SLEN + j0 + row) * EMBED + h * HDIM + kg * 4);
            float dot = S.q0s[kg*4+0]*f.x + S.q0s[kg*4+1]*f.y + S.q0s[kg*4+2]*f.z + S.q0s[kg*4+3]*f.w;
            dot += __shfl_xor(dot, 1, 64);
            dot += __shfl_xor(dot, 2, 64);
            dot += __shfl_xor(dot, 4, 64);
            dot += __shfl_xor(dot, 8, 64);
            if ((t & 15) == 0) S.wls[row] = __expf(dot * INV_SCALE);
            if (!S.m_s[row]) f = make_float4(0.f, 0.f, 0.f, 0.f);
            s16x4 o;
            o[0] = f2bf(f.x); o[1] = f2bf(f.y); o[2] = f2bf(f.z); o[3] = f2bf(f.w);
            *(s16x4*)&Kbf[fragbase + lidx(row, kg >> 1) + (kg & 1) * 4] = o;
        }

        // V chunk -> LDS (fp32, padded)
        #pragma unroll
        for (int p = 0; p < 4; ++p) {
            int idx = p * 256 + t, row = idx >> 4, kg = idx & 15;
            float4 f = *(const float4*)(v + ((size_t)b * SLEN + j0 + row) * EMBED + h * HDIM + kg * 4);
            *(float4*)&S.vbuf[row][kg * 4] = f;
        }
        __syncthreads();

        // row-0 PV + vsum partials: lane = d, wave w covers 16 j
        float num = 0.f, vs = 0.f;
        #pragma unroll
        for (int jj = 0; jj < 16; ++jj) {
            int jl = w * 16 + jj;
            float vv = S.vbuf[jl][l];
            num += S.wls[jl] * vv;
            if (S.m_s[jl]) vs += vv;
        }
        S.red[w][l] = num;
        S.redv[w][l] = vs;

        // V -> Vbf transposed frags: thread (w,l): d=l, jseg = w*2+s
        #pragma unroll
        for (int s = 0; s < 2; ++s) {
            int jseg = w * 2 + s;
            bf16x8 o;
            #pragma unroll
            for (int e = 0; e < 8; ++e) o[e] = f2bf(S.vbuf[jseg * 8 + e][l]);
            *(bf16x8*)&Vbf[fragbase + lidx(l, jseg)] = o;
        }
        __syncthreads();

        // deterministic partial writes (unique writer per slot)
        if (w == 0) {
            gnum_part[((size_t)(b * HEADS + h) * NCHUNK + c) * HDIM + l] =
                S.red[0][l] + S.red[1][l] + S.red[2][l] + S.red[3][l];
            vsum_part[((size_t)b * NCHUNK + c) * EMBED + h * HDIM + l] =
                S.redv[0][l] + S.redv[1][l] + S.redv[2][l] + S.redv[3][l];
        } else if (w == 1) {
            float s = S.wls[l];
            #pragma unroll
            for (int off = 32; off > 0; off >>= 1) s += __shfl_xor(s, off, 64);
            if (l == 0) gden_part[(size_t)(b * HEADS + h) * NCHUNK + c] = s;
        } else if (w == 2 && h == 0) {
            float cc = S.m_s[l] ? 1.f : 0.f;
            #pragma unroll
            for (int off = 32; off > 0; off >>= 1) cc += __shfl_xor(cc, off, 64);
            if (l == 0) nval_part[b * NCHUNK + c] = cc;
        }

        // fc_w tile conversion on c<4 blocks: tile (nb = b*4+c, kt = h)
        if (c < 4) {
            int nb = b * 4 + c;
            size_t base = (size_t)(nb * 8 + h) * 4096;
            #pragma unroll
            for (int p = 0; p < 4; ++p) {
                int idx = p * 256 + t, row = idx >> 4, kg = idx & 15;
                float4 f = *(const float4*)(fcw + (size_t)(nb * 64 + row) * EMBED + h * 64 + kg * 4);
                s16x4 o;
                o[0] = f2bf(f.x); o[1] = f2bf(f.y); o[2] = f2bf(f.z); o[3] = f2bf(f.w);
                *(s16x4*)&Wbf[base + lidx(row, kg >> 1) + (kg & 1) * 4] = o;
            }
        }
    }
    __threadfence();
    grid.sync();

    // ===================== phase 2: windowed attention =====================
    {
        int tile = bid & 31, h = (bid >> 5) & 7, b = bid >> 8;
        int r0 = tile * 64;
        WindowedS& S = *reinterpret_cast<WindowedS*>(smem_raw);

        size_t hb = (size_t)(b * HEADS + h) * NCHUNK;
        int bh = b * HEADS + h;

        const short* qtile = Qbf + (hb + tile) * 4096;
        bf16x8 qb0 = *(const bf16x8*)&qtile[lidx(w * 16 + lr, lg)];
        bf16x8 qb1 = *(const bf16x8*)&qtile[lidx(w * 16 + lr, 4 + lg)];

        int c0 = tile - 2; if (c0 < 0) c0 = 0;
        int c1 = tile + 2; if (c1 > NCHUNK - 1) c1 = NCHUNK - 1;

        stage_chunk(Kbf + (hb + c0) * 4096, Vbf + (hb + c0) * 4096,
                    &S.k_s[0][0], &S.v_s[0][0], t);

        // ---- reduce phase-1 partials while stage loads are in flight ----
        {
            float vp = 0.f;
            #pragma unroll
            for (int cc = 0; cc < 8; ++cc)
                vp += vsum_part[((size_t)b * NCHUNK + w * 8 + cc) * EMBED + h * HDIM + l];
            S.vred[w][l] = vp;
            if (w == 0) {
                float nvv = (l < NCHUNK) ? nval_part[b * NCHUNK + l] : 0.f;
                #pragma unroll
                for (int off = 32; off > 0; off >>= 1) nvv += __shfl_xor(nvv, off, 64);
                if (l == 0) S.nv = nvv;
            }
            if (tile == 0) {
                float gp = 0.f;
                #pragma unroll
                for (int cc = 0; cc < 8; ++cc)
                    gp += gnum_part[((size_t)bh * NCHUNK + w * 8 + cc) * HDIM + l];
                S.gred[w][l] = gp;
                if (w == 1) {
                    float gdd = (l < NCHUNK) ? gden_part[(size_t)bh * NCHUNK + l] : 0.f;
                    #pragma unroll
                    for (int off = 32; off > 0; off >>= 1) gdd += __shfl_xor(gdd, off, 64);
                    if (l == 0) S.gd = gdd;
                }
            }
        }

        int center = r0 + w * 16 + lr - 1;
        int lo = center - HALFW, hi = center + HALFW;

        f32x4 pv[4];
        #pragma unroll
        for (int dt = 0; dt < 4; ++dt) pv[dt] = (f32x4){0.f, 0.f, 0.f, 0.f};
        float dacc = 0.f;
        int cur = 0;

        asm volatile("s_waitcnt vmcnt(0)" ::: "memory");
        __syncthreads();

        for (int c = c0; c <= c1; ++c) {
            if (c < c1)
                stage_chunk(Kbf + (hb + c + 1) * 4096, Vbf + (hb + c + 1) * 4096,
                            &S.k_s[cur ^ 1][0], &S.v_s[cur ^ 1][0], t);
            int jc = c * 64;

            // QK^T (S^T): A = K rows, B = Q
            #pragma unroll
            for (int jt = 0; jt < 4; ++jt) {
                bf16x8 ka0 = *(const bf16x8*)&S.k_s[cur][lidx(jt * 16 + lr, lg)];
                bf16x8 ka1 = *(const bf16x8*)&S.k_s[cur][lidx(jt * 16 + lr, 4 + lg)];
                f32x4 sT = (f32x4){0.f, 0.f, 0.f, 0.f};
                sT = MFMA16(ka0, qb0, sT);
                sT = MFMA16(ka1, qb1, sT);
                int jbase = jc + jt * 16 + lg * 4;
                s16x4 wq;
                #pragma unroll
                for (int r = 0; r < 4; ++r) {
                    int j = jbase + r;
                    float wgt = (j >= lo && j <= hi) ? (__expf(sT[r] * INV_SCALE) - 1.f) : 0.f;
                    dacc += wgt;
                    wq[r] = f2bf(wgt);
                }
                *(s16x4*)&S.wT_s[w][lr][jt * 16 + lg * 4] = wq;
            }

            // PV: A = w^T strip (wave-private), B = V^T frags
            bf16x8 wa0 = *(const bf16x8*)&S.wT_s[w][lr][lg * 8];
            bf16x8 wa1 = *(const bf16x8*)&S.wT_s[w][lr][32 + lg * 8];
            #pragma unroll
            for (int dt = 0; dt < 4; ++dt) {
                bf16x8 va0 = *(const bf16x8*)&S.v_s[cur][lidx(dt * 16 + lr, lg)];
                bf16x8 va1 = *(const bf16x8*)&S.v_s[cur][lidx(dt * 16 + lr, 4 + lg)];
                pv[dt] = MFMA16(wa0, va0, pv[dt]);
                pv[dt] = MFMA16(wa1, va1, pv[dt]);
            }

            asm volatile("s_waitcnt vmcnt(0)" ::: "memory");
            __syncthreads();
            cur ^= 1;
        }

        // single-key fixup: row r0, key jx = r0-129
        float wfix = 0.f;
        int jx = r0 - 129;
        if (w == 0 && jx >= 0) {
            float qv = q[((size_t)b * SLEN + r0) * EMBED + h * HDIM + l];
            float kv = k[((size_t)b * SLEN + jx) * EMBED + h * HDIM + l];
            float dd = qv * kv;
            #pragma unroll
            for (int off = 32; off > 0; off >>= 1) dd += __shfl_xor(dd, off, 64);
            if (mask[b * SLEN + jx] != 0) wfix = __expf(dd * INV_SCALE) - 1.f;
            if (lg == 0) {
                #pragma unroll
                for (int dt = 0; dt < 4; ++dt)
                    pv[dt][0] += wfix * v[((size_t)b * SLEN + jx) * EMBED + h * HDIM + dt * 16 + lr];
            }
        }

        // row-sum reduce
        dacc += __shfl_xor(dacc, 16, 64);
        dacc += __shfl_xor(dacc, 32, 64);
        if (lg == 0) S.rsum[w * 16 + lr] = dacc + ((w == 0 && lr == 0) ? wfix : 0.f);
        __syncthreads();

        // epilogue: write fc-A frag tile (row 0 from global-attn reduction)
        float nv = S.nv;
        float invden[4];
        #pragma unroll
        for (int r = 0; r < 4; ++r)
            invden[r] = 1.f / (nv + S.rsum[w * 16 + lg * 4 + r]);

        short* Atile = Abf + ((size_t)(b * NCHUNK + tile) * 8 + h) * 4096;
        #pragma unroll
        for (int dt = 0; dt < 4; ++dt) {
            int d = dt * 16 + lr;
            float vs = S.vred[0][d] + S.vred[1][d] + S.vred[2][d] + S.vred[3][d];
            #pragma unroll
            for (int r = 0; r < 4; ++r) {
                int row_local = w * 16 + lg * 4 + r;
                float o;
                if (tile == 0 && row_local == 0)
                    o = (S.gred[0][d] + S.gred[1][d] + S.gred[2][d] + S.gred[3][d]) / S.gd;
                else
                    o = (pv[dt][r] + vs) * invden[r];
                Atile[lidx(row_local, d >> 3) + (d & 7)] = f2bf(o);
            }
        }
    }
    __threadfence();
    grid.sync();

    // ===================== phase 3: FC GEMM =====================
    {
        int bm = bid >> 3;            // 0..63
        int nb = bid & 7;             // 0..7
        int wr = w >> 1, wc = w & 1;
        FcS& S = *reinterpret_cast<FcS*>(smem_raw);

        f32x4 acc[2][2];
        #pragma unroll
        for (int mt = 0; mt < 2; ++mt)
            #pragma unroll
            for (int nt = 0; nt < 2; ++nt) acc[mt][nt] = (f32x4){0.f, 0.f, 0.f, 0.f};

        stage_chunk(Abf + (size_t)(bm * 8 + 0) * 4096, Wbf + (size_t)(nb * 8 + 0) * 4096,
                    &S.a_s[0][0], &S.b_s[0][0], t);
        asm volatile("s_waitcnt vmcnt(0)" ::: "memory");
        __syncthreads();
        int cur = 0;

        for (int kt = 0; kt < 8; ++kt) {
            if (kt < 7)
                stage_chunk(Abf + (size_t)(bm * 8 + kt + 1) * 4096,
                            Wbf + (size_t)(nb * 8 + kt + 1) * 4096,
                            &S.a_s[cur ^ 1][0], &S.b_s[cur ^ 1][0], t);

            bf16x8 af[2][2], bf_[2][2];
            #pragma unroll
            for (int mt = 0; mt < 2; ++mt) {
                af[mt][0] = *(const bf16x8*)&S.a_s[cur][lidx(wr * 32 + mt * 16 + lr, lg)];
                af[mt][1] = *(const bf16x8*)&S.a_s[cur][lidx(wr * 32 + mt * 16 + lr, 4 + lg)];
            }
            #pragma unroll
            for (int nt = 0; nt < 2; ++nt) {
                bf_[nt][0] = *(const bf16x8*)&S.b_s[cur][lidx(wc * 32 + nt * 16 + lr, lg)];
                bf_[nt][1] = *(const bf16x8*)&S.b_s[cur][lidx(wc * 32 + nt * 16 + lr, 4 + lg)];
            }
            #pragma unroll
            for (int mt = 0; mt < 2; ++mt)
                #pragma unroll
                for (int nt = 0; nt < 2; ++nt) {
                    acc[mt][nt] = MFMA16(af[mt][0], bf_[nt][0], acc[mt][nt]);
                    acc[mt][nt] = MFMA16(af[mt][1], bf_[nt][1], acc[mt][nt]);
                }

            asm volatile("s_waitcnt vmcnt(0)" ::: "memory");
            __syncthreads();
            cur ^= 1;
        }

        #pragma unroll
        for (int mt = 0; mt < 2; ++mt)
            #pragma unroll
            for (int nt = 0; nt < 2; ++nt) {
                int n = nb * 64 + wc * 32 + nt * 16 + lr;
                float bb = bias[n];
                #pragma unroll
                for (int reg = 0; reg < 4; ++reg) {
                    int m = bm * 64 + wr * 32 + mt * 16 + lg * 4 + reg;
                    out[(size_t)m * 512 + n] = acc[mt][nt][reg] + bb;
                }
            }
    }
}

// ---------------------------------------------------------------------------
extern "C" void kernel_launch(void* const* d_in, const int* in_sizes, int n_in,
                              void* d_out, int out_size, void* d_ws, size_t ws_size,
                              hipStream_t stream) {
    const float* values = (const float*)d_in[0];
    const float* keys   = (const float*)d_in[1];
    const float* query  = (const float*)d_in[2];
    const int*   maskp  = (const int*)d_in[3];
    const float* fc_w   = (const float*)d_in[4];
    const float* fc_b   = (const float*)d_in[5];
    float* out = (float*)d_out;

    short* Abf = (short*)d_ws;                                    // 4 MB
    short* Wbf = Abf + (size_t)BATCH * SLEN * EMBED;              // 512 KB
    short* Qbf = Wbf + (size_t)EMBED * EMBED;                     // 4 MB
    short* Kbf = Qbf + (size_t)BATCH * HEADS * NCHUNK * 4096;     // 4 MB
    short* Vbf = Kbf + (size_t)BATCH * HEADS * NCHUNK * 4096;     // 4 MB
    float* vsum_part = (float*)(Vbf + (size_t)BATCH * HEADS * NCHUNK * 4096);
    float* gnum_part = vsum_part + (size_t)BATCH * NCHUNK * EMBED;
    float* gden_part = gnum_part + (size_t)BATCH * HEADS * NCHUNK * HDIM;
    float* nval_part = gden_part + (size_t)BATCH * HEADS * NCHUNK;

    void* args[] = {
        (void*)&query, (void*)&keys, (void*)&values, (void*)&maskp,
        (void*)&fc_w, (void*)&fc_b,
        (void*)&Qbf, (void*)&Kbf, (void*)&Vbf, (void*)&Wbf, (void*)&Abf,
        (void*)&vsum_part, (void*)&gnum_part, (void*)&gden_part, (void*)&nval_part,
        (void*)&out
    };
    hipLaunchCooperativeKernel((const void*)fused_all, dim3(512), dim3(256),
                               args, 0, stream);
}

// Round 8
// 36.818 us; speedup vs baseline: 6.7054x; 6.7054x over previous
//
#include <hip/hip_runtime.h>
#include <math.h>

#define EMBED 512
#define HEADS 8
#define HDIM 64
#define SLEN 2048
#define BATCH 2
#define HALFW 128
#define NCHUNK 32
#define INV_SCALE 0.044194173824159216f  // 1/sqrt(512)

typedef short bf16x8 __attribute__((ext_vector_type(8)));
typedef short s16x4  __attribute__((ext_vector_type(4)));
typedef float f32x4  __attribute__((ext_vector_type(4)));

#define MFMA16(a, b, c) __builtin_amdgcn_mfma_f32_16x16x32_bf16(a, b, c, 0, 0, 0)

__device__ __forceinline__ short f2bf(float x) {
    union { float f; unsigned u; } v; v.f = x;
    unsigned r = v.u + 0x7FFFu + ((v.u >> 16) & 1u);  // RNE
    return (short)(r >> 16);
}

// Blocked-frag layout for a 64x64 bf16 tile (global AND LDS), XOR-swizzled:
// 16B fragment (row, seg) at short index ((seg*64) + (row^seg)) * 8.
// Frag reads & staging writes bank-conflict-free (R2-R6: SQ_LDS_BANK_CONFLICT=0).
__device__ __forceinline__ int lidx(int row, int seg) {
    return (((seg << 6) + (row ^ seg)) << 3);
}

// async global->LDS, 16B per lane. dest: wave-uniform base, HW adds lane*16.
__device__ __forceinline__ void gll16(const short* g, short* l) {
    __builtin_amdgcn_global_load_lds(
        (const __attribute__((address_space(1))) unsigned int*)g,
        (__attribute__((address_space(3))) unsigned int*)l, 16, 0, 0);
}

// identity-copy two 8KB frag tiles (layout preserved: dest off == src off)
__device__ __forceinline__ void stage_chunk(const short* s0, const short* s1,
                                            short* d0, short* d1, int t) {
    int off = t * 8;              // shorts
    int wb  = (t >> 6) * 512;     // wave-uniform LDS base (shorts)
    gll16(s0 + off,        d0 + wb);
    gll16(s0 + 2048 + off, d0 + 2048 + wb);
    gll16(s1 + off,        d1 + wb);
    gll16(s1 + 2048 + off, d1 + 2048 + wb);
}

// ---------------------------------------------------------------------------
// Kernel 1: prepass. grid (NCHUNK+4, HEADS, BATCH), 256 thr.
//  c <  NCHUNK: K/V -> frag bf16 (K rows zeroed where mask==0, V transposed);
//               row-0 global-attn partials + vsum/nvalid partials
//               (deterministic unique-writer slots, NO atomics, NO memset).
//  c >= NCHUNK: fc_w -> Wbf frag-tile conversion.
// ---------------------------------------------------------------------------
__global__ __launch_bounds__(256) void prepass(
    const float* __restrict__ q, const float* __restrict__ k,
    const float* __restrict__ v, const int* __restrict__ mask,
    const float* __restrict__ fcw,
    short* __restrict__ Kbf, short* __restrict__ Vbf, short* __restrict__ Wbf,
    float* __restrict__ gnum_part, float* __restrict__ gden_part,
    float* __restrict__ vsum_part, float* __restrict__ nval_part) {
    int c = blockIdx.x, h = blockIdx.y, b = blockIdx.z;
    int t = threadIdx.x, w = t >> 6, l = t & 63;

    if (c >= NCHUNK) {            // ---- fc_w tile (nb, kt=h) -> Wbf frags ----
        int nb = b * 4 + (c - NCHUNK);
        size_t base = (size_t)(nb * 8 + h) * 4096;
        #pragma unroll
        for (int p = 0; p < 4; ++p) {
            int idx = p * 256 + t, row = idx >> 4, kg = idx & 15;
            float4 f = *(const float4*)(fcw + (size_t)(nb * 64 + row) * EMBED + h * 64 + kg * 4);
            s16x4 o;
            o[0] = f2bf(f.x); o[1] = f2bf(f.y); o[2] = f2bf(f.z); o[3] = f2bf(f.w);
            *(s16x4*)&Wbf[base + lidx(row, kg >> 1) + (kg & 1) * 4] = o;
        }
        return;
    }

    int j0 = c * 64;
    __shared__ float q0s[HDIM];
    __shared__ float wls[64];
    __shared__ int   m_s[64];
    __shared__ float vbuf[64][68];
    __shared__ float red[4][HDIM];
    __shared__ float redv[4][HDIM];

    if (t < 64) {
        q0s[t] = q[(size_t)b * SLEN * EMBED + h * HDIM + t];
        m_s[t] = mask[b * SLEN + j0 + t];
    }
    __syncthreads();

    size_t fragbase = ((size_t)(b * HEADS + h) * NCHUNK + c) * 4096;

    // ---- K chunk -> Kbf frags (masked rows zeroed) + row-0 dot ----
    #pragma unroll
    for (int p = 0; p < 4; ++p) {
        int idx = p * 256 + t, row = idx >> 4, kg = idx & 15;
        float4 f = *(const float4*)(k + ((size_t)b * SLEN + j0 + row) * EMBED + h * HDIM + kg * 4);
        float dot = q0s[kg*4+0]*f.x + q0s[kg*4+1]*f.y + q0s[kg*4+2]*f.z + q0s[kg*4+3]*f.w;
        dot += __shfl_xor(dot, 1, 64);
        dot += __shfl_xor(dot, 2, 64);
        dot += __shfl_xor(dot, 4, 64);
        dot += __shfl_xor(dot, 8, 64);
        if ((t & 15) == 0) wls[row] = __expf(dot * INV_SCALE);
        if (!m_s[row]) f = make_float4(0.f, 0.f, 0.f, 0.f);
        s16x4 o;
        o[0] = f2bf(f.x); o[1] = f2bf(f.y); o[2] = f2bf(f.z); o[3] = f2bf(f.w);
        *(s16x4*)&Kbf[fragbase + lidx(row, kg >> 1) + (kg & 1) * 4] = o;
    }

    // ---- V chunk -> LDS (fp32, padded) ----
    #pragma unroll
    for (int p = 0; p < 4; ++p) {
        int idx = p * 256 + t, row = idx >> 4, kg = idx & 15;
        float4 f = *(const float4*)(v + ((size_t)b * SLEN + j0 + row) * EMBED + h * HDIM + kg * 4);
        *(float4*)&vbuf[row][kg * 4] = f;
    }
    __syncthreads();

    // ---- row-0 PV + vsum partials: lane = d, wave w covers 16 j ----
    float num = 0.f, vs = 0.f;
    #pragma unroll
    for (int jj = 0; jj < 16; ++jj) {
        int jl = w * 16 + jj;
        float vv = vbuf[jl][l];
        num += wls[jl] * vv;
        if (m_s[jl]) vs += vv;
    }
    red[w][l] = num;
    redv[w][l] = vs;

    // ---- V -> Vbf transposed frags: thread (w,l): d=l, jseg = w*2+s ----
    #pragma unroll
    for (int s = 0; s < 2; ++s) {
        int jseg = w * 2 + s;
        bf16x8 o;
        #pragma unroll
        for (int e = 0; e < 8; ++e) o[e] = f2bf(vbuf[jseg * 8 + e][l]);
        *(bf16x8*)&Vbf[fragbase + lidx(l, jseg)] = o;
    }
    __syncthreads();

    // ---- deterministic partial writes (unique writer per slot) ----
    if (w == 0) {
        gnum_part[((size_t)(b * HEADS + h) * NCHUNK + c) * HDIM + l] =
            red[0][l] + red[1][l] + red[2][l] + red[3][l];
        vsum_part[((size_t)b * NCHUNK + c) * EMBED + h * HDIM + l] =
            redv[0][l] + redv[1][l] + redv[2][l] + redv[3][l];
    } else if (w == 1) {
        float s = wls[l];
        #pragma unroll
        for (int off = 32; off > 0; off >>= 1) s += __shfl_xor(s, off, 64);
        if (l == 0) gden_part[(size_t)(b * HEADS + h) * NCHUNK + c] = s;
    } else if (w == 2 && h == 0) {
        float cc = m_s[l] ? 1.f : 0.f;
        #pragma unroll
        for (int off = 32; off > 0; off >>= 1) cc += __shfl_xor(cc, off, 64);
        if (l == 0) nval_part[b * NCHUNK + c] = cc;
    }
}

// ---------------------------------------------------------------------------
// Kernel 2: windowed attention v6 — S^T MFMA, gll staging, dbuf LDS.
// Q loaded fp32 directly from global in frag pattern (no Qbf). Reduces the
// prepass partials in LDS while the first K/V stage is in flight.
// Writes fc-A frag tiles; tile 0 rows 0 finalized from global-attn partials.
// ---------------------------------------------------------------------------
__global__ __launch_bounds__(256) void windowed_attn_v6(
    const float* __restrict__ q, const float* __restrict__ k,
    const float* __restrict__ v, const int* __restrict__ mask,
    const short* __restrict__ Kbf, const short* __restrict__ Vbf,
    const float* __restrict__ gnum_part, const float* __restrict__ gden_part,
    const float* __restrict__ vsum_part, const float* __restrict__ nval_part,
    short* __restrict__ Abf) {
    int tile = blockIdx.x, h = blockIdx.y, b = blockIdx.z;
    int r0 = tile * 64;
    int t = threadIdx.x, w = t >> 6, l = t & 63;
    int lg = l >> 4, lr = l & 15;

    __shared__ __align__(16) short k_s[2][4096];
    __shared__ __align__(16) short v_s[2][4096];
    __shared__ __align__(16) short wT_s[4][16][72];
    __shared__ float rsum[64];
    __shared__ float vred[4][64];
    __shared__ float gred[4][64];
    __shared__ float nv_s, gd_s;

    size_t hb = (size_t)(b * HEADS + h) * NCHUNK;
    int bh = b * HEADS + h;

    int c0 = tile - 2; if (c0 < 0) c0 = 0;
    int c1 = tile + 2; if (c1 > NCHUNK - 1) c1 = NCHUNK - 1;

    stage_chunk(Kbf + (hb + c0) * 4096, Vbf + (hb + c0) * 4096,
                &k_s[0][0], &v_s[0][0], t);

    // ---- Q frags direct from global (fp32 -> bf16 in-register) ----
    const float* qrow = q + ((size_t)b * SLEN + r0 + w * 16 + lr) * EMBED + h * HDIM;
    float4 a0 = *(const float4*)(qrow + lg * 8);
    float4 a1 = *(const float4*)(qrow + lg * 8 + 4);
    float4 a2 = *(const float4*)(qrow + 32 + lg * 8);
    float4 a3 = *(const float4*)(qrow + 32 + lg * 8 + 4);
    bf16x8 qb0, qb1;
    qb0[0] = f2bf(a0.x); qb0[1] = f2bf(a0.y); qb0[2] = f2bf(a0.z); qb0[3] = f2bf(a0.w);
    qb0[4] = f2bf(a1.x); qb0[5] = f2bf(a1.y); qb0[6] = f2bf(a1.z); qb0[7] = f2bf(a1.w);
    qb1[0] = f2bf(a2.x); qb1[1] = f2bf(a2.y); qb1[2] = f2bf(a2.z); qb1[3] = f2bf(a2.w);
    qb1[4] = f2bf(a3.x); qb1[5] = f2bf(a3.y); qb1[6] = f2bf(a3.z); qb1[7] = f2bf(a3.w);

    // ---- reduce prepass partials while stage loads are in flight ----
    {
        float vp = 0.f;
        #pragma unroll
        for (int cc = 0; cc < 8; ++cc)
            vp += vsum_part[((size_t)b * NCHUNK + w * 8 + cc) * EMBED + h * HDIM + l];
        vred[w][l] = vp;
        if (w == 0) {
            float nvv = (l < NCHUNK) ? nval_part[b * NCHUNK + l] : 0.f;
            #pragma unroll
            for (int off = 32; off > 0; off >>= 1) nvv += __shfl_xor(nvv, off, 64);
            if (l == 0) nv_s = nvv;
        }
        if (tile == 0) {
            float gp = 0.f;
            #pragma unroll
            for (int cc = 0; cc < 8; ++cc)
                gp += gnum_part[((size_t)bh * NCHUNK + w * 8 + cc) * HDIM + l];
            gred[w][l] = gp;
            if (w == 1) {
                float gdd = (l < NCHUNK) ? gden_part[(size_t)bh * NCHUNK + l] : 0.f;
                #pragma unroll
                for (int off = 32; off > 0; off >>= 1) gdd += __shfl_xor(gdd, off, 64);
                if (l == 0) gd_s = gdd;
            }
        }
    }

    int center = r0 + w * 16 + lr - 1;
    int lo = center - HALFW, hi = center + HALFW;

    f32x4 pv[4];
    #pragma unroll
    for (int dt = 0; dt < 4; ++dt) pv[dt] = (f32x4){0.f, 0.f, 0.f, 0.f};
    float dacc = 0.f;
    int cur = 0;

    asm volatile("s_waitcnt vmcnt(0)" ::: "memory");
    __syncthreads();

    for (int c = c0; c <= c1; ++c) {
        if (c < c1)
            stage_chunk(Kbf + (hb + c + 1) * 4096, Vbf + (hb + c + 1) * 4096,
                        &k_s[cur ^ 1][0], &v_s[cur ^ 1][0], t);
        int jc = c * 64;

        // ---- QK^T (S^T): A = K rows, B = Q ----
        #pragma unroll
        for (int jt = 0; jt < 4; ++jt) {
            bf16x8 ka0 = *(const bf16x8*)&k_s[cur][lidx(jt * 16 + lr, lg)];
            bf16x8 ka1 = *(const bf16x8*)&k_s[cur][lidx(jt * 16 + lr, 4 + lg)];
            f32x4 sT = (f32x4){0.f, 0.f, 0.f, 0.f};
            sT = MFMA16(ka0, qb0, sT);
            sT = MFMA16(ka1, qb1, sT);
            int jbase = jc + jt * 16 + lg * 4;
            s16x4 wq;
            #pragma unroll
            for (int r = 0; r < 4; ++r) {
                int j = jbase + r;
                float wgt = (j >= lo && j <= hi) ? (__expf(sT[r] * INV_SCALE) - 1.f) : 0.f;
                dacc += wgt;
                wq[r] = f2bf(wgt);
            }
            *(s16x4*)&wT_s[w][lr][jt * 16 + lg * 4] = wq;
        }

        // ---- PV: A = w^T strip (wave-private), B = V^T frags ----
        bf16x8 wa0 = *(const bf16x8*)&wT_s[w][lr][lg * 8];
        bf16x8 wa1 = *(const bf16x8*)&wT_s[w][lr][32 + lg * 8];
        #pragma unroll
        for (int dt = 0; dt < 4; ++dt) {
            bf16x8 va0 = *(const bf16x8*)&v_s[cur][lidx(dt * 16 + lr, lg)];
            bf16x8 va1 = *(const bf16x8*)&v_s[cur][lidx(dt * 16 + lr, 4 + lg)];
            pv[dt] = MFMA16(wa0, va0, pv[dt]);
            pv[dt] = MFMA16(wa1, va1, pv[dt]);
        }

        asm volatile("s_waitcnt vmcnt(0)" ::: "memory");
        __syncthreads();
        cur ^= 1;
    }

    // ---- single-key fixup: row r0, key jx = r0-129 ----
    float wfix = 0.f;
    int jx = r0 - 129;
    if (w == 0 && jx >= 0) {
        float qv = q[((size_t)b * SLEN + r0) * EMBED + h * HDIM + l];
        float kv = k[((size_t)b * SLEN + jx) * EMBED + h * HDIM + l];
        float dd = qv * kv;
        #pragma unroll
        for (int off = 32; off > 0; off >>= 1) dd += __shfl_xor(dd, off, 64);
        if (mask[b * SLEN + jx] != 0) wfix = __expf(dd * INV_SCALE) - 1.f;
        if (lg == 0) {
            #pragma unroll
            for (int dt = 0; dt < 4; ++dt)
                pv[dt][0] += wfix * v[((size_t)b * SLEN + jx) * EMBED + h * HDIM + dt * 16 + lr];
        }
    }

    // ---- row-sum reduce ----
    dacc += __shfl_xor(dacc, 16, 64);
    dacc += __shfl_xor(dacc, 32, 64);
    if (lg == 0) rsum[w * 16 + lr] = dacc + ((w == 0 && lr == 0) ? wfix : 0.f);
    __syncthreads();

    // ---- epilogue: write fc-A frag tile (row 0 from global-attn partials) ----
    float nv = nv_s;
    float invden[4];
    #pragma unroll
    for (int r = 0; r < 4; ++r)
        invden[r] = 1.f / (nv + rsum[w * 16 + lg * 4 + r]);

    short* Atile = Abf + ((size_t)(b * NCHUNK + tile) * 8 + h) * 4096;
    #pragma unroll
    for (int dt = 0; dt < 4; ++dt) {
        int d = dt * 16 + lr;
        float vs = vred[0][d] + vred[1][d] + vred[2][d] + vred[3][d];
        #pragma unroll
        for (int r = 0; r < 4; ++r) {
            int row_local = w * 16 + lg * 4 + r;
            float o;
            if (tile == 0 && row_local == 0)
                o = (gred[0][d] + gred[1][d] + gred[2][d] + gred[3][d]) / gd_s;
            else
                o = (pv[dt][r] + vs) * invden[r];
            Atile[lidx(row_local, d >> 3) + (d & 7)] = f2bf(o);
        }
    }
}

// ---------------------------------------------------------------------------
// Kernel 3: FC GEMM v3 — frag-tile inputs, gll16 dbuf staging, 1 barrier/K-tile.
// ---------------------------------------------------------------------------
__global__ __launch_bounds__(256) void fc_gemm_v3(
    const short* __restrict__ Abf, const short* __restrict__ Wbf,
    const float* __restrict__ bias, float* __restrict__ C) {
    int bm = blockIdx.x;          // 0..63
    int nb = blockIdx.y;          // 0..7
    int t = threadIdx.x, w = t >> 6, l = t & 63;
    int lg = l >> 4, lr = l & 15;
    int wr = w >> 1, wc = w & 1;

    __shared__ __align__(16) short a_s[2][4096];
    __shared__ __align__(16) short b_s[2][4096];

    f32x4 acc[2][2];
    #pragma unroll
    for (int mt = 0; mt < 2; ++mt)
        #pragma unroll
        for (int nt = 0; nt < 2; ++nt) acc[mt][nt] = (f32x4){0.f, 0.f, 0.f, 0.f};

    stage_chunk(Abf + (size_t)(bm * 8 + 0) * 4096, Wbf + (size_t)(nb * 8 + 0) * 4096,
                &a_s[0][0], &b_s[0][0], t);
    asm volatile("s_waitcnt vmcnt(0)" ::: "memory");
    __syncthreads();
    int cur = 0;

    for (int kt = 0; kt < 8; ++kt) {
        if (kt < 7)
            stage_chunk(Abf + (size_t)(bm * 8 + kt + 1) * 4096,
                        Wbf + (size_t)(nb * 8 + kt + 1) * 4096,
                        &a_s[cur ^ 1][0], &b_s[cur ^ 1][0], t);

        bf16x8 af[2][2], bf_[2][2];
        #pragma unroll
        for (int mt = 0; mt < 2; ++mt) {
            af[mt][0] = *(const bf16x8*)&a_s[cur][lidx(wr * 32 + mt * 16 + lr, lg)];
            af[mt][1] = *(const bf16x8*)&a_s[cur][lidx(wr * 32 + mt * 16 + lr, 4 + lg)];
        }
        #pragma unroll
        for (int nt = 0; nt < 2; ++nt) {
            bf_[nt][0] = *(const bf16x8*)&b_s[cur][lidx(wc * 32 + nt * 16 + lr, lg)];
            bf_[nt][1] = *(const bf16x8*)&b_s[cur][lidx(wc * 32 + nt * 16 + lr, 4 + lg)];
        }
        #pragma unroll
        for (int mt = 0; mt < 2; ++mt)
            #pragma unroll
            for (int nt = 0; nt < 2; ++nt) {
                acc[mt][nt] = MFMA16(af[mt][0], bf_[nt][0], acc[mt][nt]);
                acc[mt][nt] = MFMA16(af[mt][1], bf_[nt][1], acc[mt][nt]);
            }

        asm volatile("s_waitcnt vmcnt(0)" ::: "memory");
        __syncthreads();
        cur ^= 1;
    }

    #pragma unroll
    for (int mt = 0; mt < 2; ++mt)
        #pragma unroll
        for (int nt = 0; nt < 2; ++nt) {
            int n = nb * 64 + wc * 32 + nt * 16 + lr;
            float bb = bias[n];
            #pragma unroll
            for (int reg = 0; reg < 4; ++reg) {
                int m = bm * 64 + wr * 32 + mt * 16 + lg * 4 + reg;
                C[(size_t)m * 512 + n] = acc[mt][nt][reg] + bb;
            }
        }
}

// ---------------------------------------------------------------------------
extern "C" void kernel_launch(void* const* d_in, const int* in_sizes, int n_in,
                              void* d_out, int out_size, void* d_ws, size_t ws_size,
                              hipStream_t stream) {
    const float* values = (const float*)d_in[0];
    const float* keys   = (const float*)d_in[1];
    const float* query  = (const float*)d_in[2];
    const int*   maskp  = (const int*)d_in[3];
    const float* fc_w   = (const float*)d_in[4];
    const float* fc_b   = (const float*)d_in[5];
    float* out = (float*)d_out;

    short* Abf = (short*)d_ws;                                    // 4 MB
    short* Wbf = Abf + (size_t)BATCH * SLEN * EMBED;              // 512 KB
    short* Kbf = Wbf + (size_t)EMBED * EMBED;                     // 4 MB
    short* Vbf = Kbf + (size_t)BATCH * HEADS * NCHUNK * 4096;     // 4 MB
    float* vsum_part = (float*)(Vbf + (size_t)BATCH * HEADS * NCHUNK * 4096);
    float* gnum_part = vsum_part + (size_t)BATCH * NCHUNK * EMBED;
    float* gden_part = gnum_part + (size_t)BATCH * HEADS * NCHUNK * HDIM;
    float* nval_part = gden_part + (size_t)BATCH * HEADS * NCHUNK;

    prepass<<<dim3(NCHUNK + 4, HEADS, BATCH), 256, 0, stream>>>(
        query, keys, values, maskp, fc_w, Kbf, Vbf, Wbf,
        gnum_part, gden_part, vsum_part, nval_part);
    windowed_attn_v6<<<dim3(NCHUNK, HEADS, BATCH), 256, 0, stream>>>(
        query, keys, values, maskp, Kbf, Vbf,
        gnum_part, gden_part, vsum_part, nval_part, Abf);
    fc_gemm_v3<<<dim3(BATCH * NCHUNK, EMBED / 64), 256, 0, stream>>>(
        Abf, Wbf, fc_b, out);
}

// Round 9
// 34.909 us; speedup vs baseline: 7.0720x; 1.0547x over previous
//
#include <hip/hip_runtime.h>
#include <math.h>

#define EMBED 512
#define HEADS 8
#define HDIM 64
#define SLEN 2048
#define BATCH 2
#define HALFW 128
#define NCHUNK 32
#define INV_SCALE 0.044194173824159216f  // 1/sqrt(512)

typedef short bf16x8 __attribute__((ext_vector_type(8)));
typedef short s16x4  __attribute__((ext_vector_type(4)));
typedef float f32x4  __attribute__((ext_vector_type(4)));

#define MFMA16(a, b, c) __builtin_amdgcn_mfma_f32_16x16x32_bf16(a, b, c, 0, 0, 0)

__device__ __forceinline__ short f2bf(float x) {
    union { float f; unsigned u; } v; v.f = x;
    unsigned r = v.u + 0x7FFFu + ((v.u >> 16) & 1u);  // RNE
    return (short)(r >> 16);
}

// Blocked-frag layout for a 64x64 bf16 tile (global AND LDS), XOR-swizzled:
// 16B fragment (row, seg) at short index ((seg*64) + (row^seg)) * 8.
// Frag reads & staging writes bank-conflict-free (R2-R8: SQ_LDS_BANK_CONFLICT=0).
__device__ __forceinline__ int lidx(int row, int seg) {
    return (((seg << 6) + (row ^ seg)) << 3);
}

// async global->LDS, 16B per lane. dest: wave-uniform base, HW adds lane*16.
__device__ __forceinline__ void gll16(const short* g, short* l) {
    __builtin_amdgcn_global_load_lds(
        (const __attribute__((address_space(1))) unsigned int*)g,
        (__attribute__((address_space(3))) unsigned int*)l, 16, 0, 0);
}

// identity-copy two 8KB frag tiles (layout preserved: dest off == src off)
__device__ __forceinline__ void stage_chunk(const short* s0, const short* s1,
                                            short* d0, short* d1, int t) {
    int off = t * 8;              // shorts
    int wb  = (t >> 6) * 512;     // wave-uniform LDS base (shorts)
    gll16(s0 + off,        d0 + wb);
    gll16(s0 + 2048 + off, d0 + 2048 + wb);
    gll16(s1 + off,        d1 + wb);
    gll16(s1 + 2048 + off, d1 + 2048 + wb);
}

// ---------------------------------------------------------------------------
// Kernel 1: prepass (unchanged from R8). grid (NCHUNK+4, HEADS, BATCH), 256 thr.
// ---------------------------------------------------------------------------
__global__ __launch_bounds__(256) void prepass(
    const float* __restrict__ q, const float* __restrict__ k,
    const float* __restrict__ v, const int* __restrict__ mask,
    const float* __restrict__ fcw,
    short* __restrict__ Kbf, short* __restrict__ Vbf, short* __restrict__ Wbf,
    float* __restrict__ gnum_part, float* __restrict__ gden_part,
    float* __restrict__ vsum_part, float* __restrict__ nval_part) {
    int c = blockIdx.x, h = blockIdx.y, b = blockIdx.z;
    int t = threadIdx.x, w = t >> 6, l = t & 63;

    if (c >= NCHUNK) {            // ---- fc_w tile (nb, kt=h) -> Wbf frags ----
        int nb = b * 4 + (c - NCHUNK);
        size_t base = (size_t)(nb * 8 + h) * 4096;
        #pragma unroll
        for (int p = 0; p < 4; ++p) {
            int idx = p * 256 + t, row = idx >> 4, kg = idx & 15;
            float4 f = *(const float4*)(fcw + (size_t)(nb * 64 + row) * EMBED + h * 64 + kg * 4);
            s16x4 o;
            o[0] = f2bf(f.x); o[1] = f2bf(f.y); o[2] = f2bf(f.z); o[3] = f2bf(f.w);
            *(s16x4*)&Wbf[base + lidx(row, kg >> 1) + (kg & 1) * 4] = o;
        }
        return;
    }

    int j0 = c * 64;
    __shared__ float q0s[HDIM];
    __shared__ float wls[64];
    __shared__ int   m_s[64];
    __shared__ float vbuf[64][68];
    __shared__ float red[4][HDIM];
    __shared__ float redv[4][HDIM];

    if (t < 64) {
        q0s[t] = q[(size_t)b * SLEN * EMBED + h * HDIM + t];
        m_s[t] = mask[b * SLEN + j0 + t];
    }
    __syncthreads();

    size_t fragbase = ((size_t)(b * HEADS + h) * NCHUNK + c) * 4096;

    #pragma unroll
    for (int p = 0; p < 4; ++p) {
        int idx = p * 256 + t, row = idx >> 4, kg = idx & 15;
        float4 f = *(const float4*)(k + ((size_t)b * SLEN + j0 + row) * EMBED + h * HDIM + kg * 4);
        float dot = q0s[kg*4+0]*f.x + q0s[kg*4+1]*f.y + q0s[kg*4+2]*f.z + q0s[kg*4+3]*f.w;
        dot += __shfl_xor(dot, 1, 64);
        dot += __shfl_xor(dot, 2, 64);
        dot += __shfl_xor(dot, 4, 64);
        dot += __shfl_xor(dot, 8, 64);
        if ((t & 15) == 0) wls[row] = __expf(dot * INV_SCALE);
        if (!m_s[row]) f = make_float4(0.f, 0.f, 0.f, 0.f);
        s16x4 o;
        o[0] = f2bf(f.x); o[1] = f2bf(f.y); o[2] = f2bf(f.z); o[3] = f2bf(f.w);
        *(s16x4*)&Kbf[fragbase + lidx(row, kg >> 1) + (kg & 1) * 4] = o;
    }

    #pragma unroll
    for (int p = 0; p < 4; ++p) {
        int idx = p * 256 + t, row = idx >> 4, kg = idx & 15;
        float4 f = *(const float4*)(v + ((size_t)b * SLEN + j0 + row) * EMBED + h * HDIM + kg * 4);
        *(float4*)&vbuf[row][kg * 4] = f;
    }
    __syncthreads();

    float num = 0.f, vs = 0.f;
    #pragma unroll
    for (int jj = 0; jj < 16; ++jj) {
        int jl = w * 16 + jj;
        float vv = vbuf[jl][l];
        num += wls[jl] * vv;
        if (m_s[jl]) vs += vv;
    }
    red[w][l] = num;
    redv[w][l] = vs;

    #pragma unroll
    for (int s = 0; s < 2; ++s) {
        int jseg = w * 2 + s;
        bf16x8 o;
        #pragma unroll
        for (int e = 0; e < 8; ++e) o[e] = f2bf(vbuf[jseg * 8 + e][l]);
        *(bf16x8*)&Vbf[fragbase + lidx(l, jseg)] = o;
    }
    __syncthreads();

    if (w == 0) {
        gnum_part[((size_t)(b * HEADS + h) * NCHUNK + c) * HDIM + l] =
            red[0][l] + red[1][l] + red[2][l] + red[3][l];
        vsum_part[((size_t)b * NCHUNK + c) * EMBED + h * HDIM + l] =
            redv[0][l] + redv[1][l] + redv[2][l] + redv[3][l];
    } else if (w == 1) {
        float s = wls[l];
        #pragma unroll
        for (int off = 32; off > 0; off >>= 1) s += __shfl_xor(s, off, 64);
        if (l == 0) gden_part[(size_t)(b * HEADS + h) * NCHUNK + c] = s;
    } else if (w == 2 && h == 0) {
        float cc = m_s[l] ? 1.f : 0.f;
        #pragma unroll
        for (int off = 32; off > 0; off >>= 1) cc += __shfl_xor(cc, off, 64);
        if (l == 0) nval_part[b * NCHUNK + c] = cc;
    }
}

// ---------------------------------------------------------------------------
// Kernel 2: windowed attention v7 — 3-buffer K/V, counted vmcnt (2-ahead),
// ONE barrier per chunk, no drains. q converted pre-staging so only gll16s
// occupy the vmcnt FIFO inside the loop (in-order retirement).
// ---------------------------------------------------------------------------
__global__ __launch_bounds__(256) void windowed_attn_v7(
    const float* __restrict__ q, const float* __restrict__ k,
    const float* __restrict__ v, const int* __restrict__ mask,
    const short* __restrict__ Kbf, const short* __restrict__ Vbf,
    const float* __restrict__ gnum_part, const float* __restrict__ gden_part,
    const float* __restrict__ vsum_part, const float* __restrict__ nval_part,
    short* __restrict__ Abf) {
    int tile = blockIdx.x, h = blockIdx.y, b = blockIdx.z;
    int r0 = tile * 64;
    int t = threadIdx.x, w = t >> 6, l = t & 63;
    int lg = l >> 4, lr = l & 15;

    __shared__ __align__(16) short k_s[3][4096];
    __shared__ __align__(16) short v_s[3][4096];
    __shared__ __align__(16) short wT_s[4][16][72];
    __shared__ float rsum[64];
    __shared__ float vred[4][64];
    __shared__ float gred[4][64];
    __shared__ float nv_s, gd_s;

    size_t hb = (size_t)(b * HEADS + h) * NCHUNK;
    int bh = b * HEADS + h;

    int c0 = tile - 2; if (c0 < 0) c0 = 0;
    int c1 = tile + 2; if (c1 > NCHUNK - 1) c1 = NCHUNK - 1;
    // >= 3 chunks always, so prologue can stage 2 unconditionally.

    stage_chunk(Kbf + (hb + c0) * 4096, Vbf + (hb + c0) * 4096,
                &k_s[0][0], &v_s[0][0], t);

    // ---- Q frags direct from global (fp32 -> bf16), consumed BEFORE loop ----
    const float* qrow = q + ((size_t)b * SLEN + r0 + w * 16 + lr) * EMBED + h * HDIM;
    float4 a0 = *(const float4*)(qrow + lg * 8);
    float4 a1 = *(const float4*)(qrow + lg * 8 + 4);
    float4 a2 = *(const float4*)(qrow + 32 + lg * 8);
    float4 a3 = *(const float4*)(qrow + 32 + lg * 8 + 4);
    bf16x8 qb0, qb1;
    qb0[0] = f2bf(a0.x); qb0[1] = f2bf(a0.y); qb0[2] = f2bf(a0.z); qb0[3] = f2bf(a0.w);
    qb0[4] = f2bf(a1.x); qb0[5] = f2bf(a1.y); qb0[6] = f2bf(a1.z); qb0[7] = f2bf(a1.w);
    qb1[0] = f2bf(a2.x); qb1[1] = f2bf(a2.y); qb1[2] = f2bf(a2.z); qb1[3] = f2bf(a2.w);
    qb1[4] = f2bf(a3.x); qb1[5] = f2bf(a3.y); qb1[6] = f2bf(a3.z); qb1[7] = f2bf(a3.w);

    // ---- reduce prepass partials (loads retired here, before the loop) ----
    {
        float vp = 0.f;
        #pragma unroll
        for (int cc = 0; cc < 8; ++cc)
            vp += vsum_part[((size_t)b * NCHUNK + w * 8 + cc) * EMBED + h * HDIM + l];
        vred[w][l] = vp;
        if (w == 0) {
            float nvv = (l < NCHUNK) ? nval_part[b * NCHUNK + l] : 0.f;
            #pragma unroll
            for (int off = 32; off > 0; off >>= 1) nvv += __shfl_xor(nvv, off, 64);
            if (l == 0) nv_s = nvv;
        }
        if (tile == 0) {
            float gp = 0.f;
            #pragma unroll
            for (int cc = 0; cc < 8; ++cc)
                gp += gnum_part[((size_t)bh * NCHUNK + w * 8 + cc) * HDIM + l];
            gred[w][l] = gp;
            if (w == 1) {
                float gdd = (l < NCHUNK) ? gden_part[(size_t)bh * NCHUNK + l] : 0.f;
                #pragma unroll
                for (int off = 32; off > 0; off >>= 1) gdd += __shfl_xor(gdd, off, 64);
                if (l == 0) gd_s = gdd;
            }
        }
    }

    stage_chunk(Kbf + (hb + c0 + 1) * 4096, Vbf + (hb + c0 + 1) * 4096,
                &k_s[1][0], &v_s[1][0], t);

    int center = r0 + w * 16 + lr - 1;
    int lo = center - HALFW, hi = center + HALFW;

    f32x4 pv[4];
    #pragma unroll
    for (int dt = 0; dt < 4; ++dt) pv[dt] = (f32x4){0.f, 0.f, 0.f, 0.f};
    float dacc = 0.f;

    int bi = 0;
    for (int c = c0; c <= c1; ++c) {
        // wait for stage(c): everything except the newest stage (c+1) if present
        if (c < c1) { asm volatile("s_waitcnt vmcnt(4)" ::: "memory"); }
        else        { asm volatile("s_waitcnt vmcnt(0)" ::: "memory"); }
        __syncthreads();

        int jc = c * 64;
        // ---- QK^T (S^T): A = K rows, B = Q ----
        #pragma unroll
        for (int jt = 0; jt < 4; ++jt) {
            bf16x8 ka0 = *(const bf16x8*)&k_s[bi][lidx(jt * 16 + lr, lg)];
            bf16x8 ka1 = *(const bf16x8*)&k_s[bi][lidx(jt * 16 + lr, 4 + lg)];
            f32x4 sT = (f32x4){0.f, 0.f, 0.f, 0.f};
            sT = MFMA16(ka0, qb0, sT);
            sT = MFMA16(ka1, qb1, sT);
            int jbase = jc + jt * 16 + lg * 4;
            s16x4 wq;
            #pragma unroll
            for (int r = 0; r < 4; ++r) {
                int j = jbase + r;
                float wgt = (j >= lo && j <= hi) ? (__expf(sT[r] * INV_SCALE) - 1.f) : 0.f;
                dacc += wgt;
                wq[r] = f2bf(wgt);
            }
            *(s16x4*)&wT_s[w][lr][jt * 16 + lg * 4] = wq;
        }

        // ---- PV: A = w^T strip (wave-private), B = V^T frags ----
        bf16x8 wa0 = *(const bf16x8*)&wT_s[w][lr][lg * 8];
        bf16x8 wa1 = *(const bf16x8*)&wT_s[w][lr][32 + lg * 8];
        #pragma unroll
        for (int dt = 0; dt < 4; ++dt) {
            bf16x8 va0 = *(const bf16x8*)&v_s[bi][lidx(dt * 16 + lr, lg)];
            bf16x8 va1 = *(const bf16x8*)&v_s[bi][lidx(dt * 16 + lr, 4 + lg)];
            pv[dt] = MFMA16(wa0, va0, pv[dt]);
            pv[dt] = MFMA16(wa1, va1, pv[dt]);
        }

        // stage chunk c+2 into buffer (bi+2)%3 = buffer of compute(c-1);
        // safe: every wave passed this iter's barrier only after finishing c-1.
        if (c + 2 <= c1) {
            int bn = bi + 2; if (bn >= 3) bn -= 3;
            stage_chunk(Kbf + (hb + c + 2) * 4096, Vbf + (hb + c + 2) * 4096,
                        &k_s[bn][0], &v_s[bn][0], t);
        }
        ++bi; if (bi == 3) bi = 0;
    }

    // ---- single-key fixup: row r0, key jx = r0-129 ----
    float wfix = 0.f;
    int jx = r0 - 129;
    if (w == 0 && jx >= 0) {
        float qv = q[((size_t)b * SLEN + r0) * EMBED + h * HDIM + l];
        float kv = k[((size_t)b * SLEN + jx) * EMBED + h * HDIM + l];
        float dd = qv * kv;
        #pragma unroll
        for (int off = 32; off > 0; off >>= 1) dd += __shfl_xor(dd, off, 64);
        if (mask[b * SLEN + jx] != 0) wfix = __expf(dd * INV_SCALE) - 1.f;
        if (lg == 0) {
            #pragma unroll
            for (int dt = 0; dt < 4; ++dt)
                pv[dt][0] += wfix * v[((size_t)b * SLEN + jx) * EMBED + h * HDIM + dt * 16 + lr];
        }
    }

    // ---- row-sum reduce ----
    dacc += __shfl_xor(dacc, 16, 64);
    dacc += __shfl_xor(dacc, 32, 64);
    if (lg == 0) rsum[w * 16 + lr] = dacc + ((w == 0 && lr == 0) ? wfix : 0.f);
    __syncthreads();

    // ---- epilogue: write fc-A frag tile (row 0 from global-attn partials) ----
    float nv = nv_s;
    float invden[4];
    #pragma unroll
    for (int r = 0; r < 4; ++r)
        invden[r] = 1.f / (nv + rsum[w * 16 + lg * 4 + r]);

    short* Atile = Abf + ((size_t)(b * NCHUNK + tile) * 8 + h) * 4096;
    #pragma unroll
    for (int dt = 0; dt < 4; ++dt) {
        int d = dt * 16 + lr;
        float vs = vred[0][d] + vred[1][d] + vred[2][d] + vred[3][d];
        #pragma unroll
        for (int r = 0; r < 4; ++r) {
            int row_local = w * 16 + lg * 4 + r;
            float o;
            if (tile == 0 && row_local == 0)
                o = (gred[0][d] + gred[1][d] + gred[2][d] + gred[3][d]) / gd_s;
            else
                o = (pv[dt][r] + vs) * invden[r];
            Atile[lidx(row_local, d >> 3) + (d & 7)] = f2bf(o);
        }
    }
}

// ---------------------------------------------------------------------------
// Kernel 3: FC GEMM v4 — A-strip staged once (64 KB), W double-buffered with
// counted vmcnt; no drains in the K loop. LDS 80 KB -> 2 blocks/CU.
// ---------------------------------------------------------------------------
__global__ __launch_bounds__(256) void fc_gemm_v4(
    const short* __restrict__ Abf, const short* __restrict__ Wbf,
    const float* __restrict__ bias, float* __restrict__ C) {
    int bm = blockIdx.x;          // 0..63
    int nb = blockIdx.y;          // 0..7
    int t = threadIdx.x, w = t >> 6, l = t & 63;
    int lg = l >> 4, lr = l & 15;
    int wr = w >> 1, wc = w & 1;

    __shared__ __align__(16) short a_s[8][4096];   // full A strip (64 KB)
    __shared__ __align__(16) short w_s[2][4096];   // W dbuf (16 KB)

    int off = t * 8;
    int wb  = (t >> 6) * 512;

    // prologue: stage whole A strip, then W0, W1 (issue order = retire order)
    #pragma unroll
    for (int kt = 0; kt < 8; ++kt) {
        const short* as = Abf + (size_t)(bm * 8 + kt) * 4096;
        gll16(as + off,        &a_s[kt][wb]);
        gll16(as + 2048 + off, &a_s[kt][2048 + wb]);
    }
    {
        const short* ws0 = Wbf + (size_t)(nb * 8 + 0) * 4096;
        gll16(ws0 + off,        &w_s[0][wb]);
        gll16(ws0 + 2048 + off, &w_s[0][2048 + wb]);
        const short* ws1 = Wbf + (size_t)(nb * 8 + 1) * 4096;
        gll16(ws1 + off,        &w_s[1][wb]);
        gll16(ws1 + 2048 + off, &w_s[1][2048 + wb]);
    }

    f32x4 acc[2][2];
    #pragma unroll
    for (int mt = 0; mt < 2; ++mt)
        #pragma unroll
        for (int nt = 0; nt < 2; ++nt) acc[mt][nt] = (f32x4){0.f, 0.f, 0.f, 0.f};

    for (int kt = 0; kt < 8; ++kt) {
        // wait A strip + W(kt); W(kt+1) (2 newest) may stay in flight
        if (kt < 7) { asm volatile("s_waitcnt vmcnt(2)" ::: "memory"); }
        else        { asm volatile("s_waitcnt vmcnt(0)" ::: "memory"); }
        __syncthreads();

        bf16x8 af[2][2], bf_[2][2];
        #pragma unroll
        for (int mt = 0; mt < 2; ++mt) {
            af[mt][0] = *(const bf16x8*)&a_s[kt][lidx(wr * 32 + mt * 16 + lr, lg)];
            af[mt][1] = *(const bf16x8*)&a_s[kt][lidx(wr * 32 + mt * 16 + lr, 4 + lg)];
        }
        int wbuf = kt & 1;
        #pragma unroll
        for (int nt = 0; nt < 2; ++nt) {
            bf_[nt][0] = *(const bf16x8*)&w_s[wbuf][lidx(wc * 32 + nt * 16 + lr, lg)];
            bf_[nt][1] = *(const bf16x8*)&w_s[wbuf][lidx(wc * 32 + nt * 16 + lr, 4 + lg)];
        }
        #pragma unroll
        for (int mt = 0; mt < 2; ++mt)
            #pragma unroll
            for (int nt = 0; nt < 2; ++nt) {
                acc[mt][nt] = MFMA16(af[mt][0], bf_[nt][0], acc[mt][nt]);
                acc[mt][nt] = MFMA16(af[mt][1], bf_[nt][1], acc[mt][nt]);
            }

        __syncthreads();   // all waves done reading w_s[wbuf] before restage
        if (kt + 2 <= 7) {
            const short* ws = Wbf + (size_t)(nb * 8 + kt + 2) * 4096;
            gll16(ws + off,        &w_s[wbuf][wb]);
            gll16(ws + 2048 + off, &w_s[wbuf][2048 + wb]);
        }
    }

    #pragma unroll
    for (int mt = 0; mt < 2; ++mt)
        #pragma unroll
        for (int nt = 0; nt < 2; ++nt) {
            int n = nb * 64 + wc * 32 + nt * 16 + lr;
            float bb = bias[n];
            #pragma unroll
            for (int reg = 0; reg < 4; ++reg) {
                int m = bm * 64 + wr * 32 + mt * 16 + lg * 4 + reg;
                C[(size_t)m * 512 + n] = acc[mt][nt][reg] + bb;
            }
        }
}

// ---------------------------------------------------------------------------
extern "C" void kernel_launch(void* const* d_in, const int* in_sizes, int n_in,
                              void* d_out, int out_size, void* d_ws, size_t ws_size,
                              hipStream_t stream) {
    const float* values = (const float*)d_in[0];
    const float* keys   = (const float*)d_in[1];
    const float* query  = (const float*)d_in[2];
    const int*   maskp  = (const int*)d_in[3];
    const float* fc_w   = (const float*)d_in[4];
    const float* fc_b   = (const float*)d_in[5];
    float* out = (float*)d_out;

    short* Abf = (short*)d_ws;                                    // 4 MB
    short* Wbf = Abf + (size_t)BATCH * SLEN * EMBED;              // 512 KB
    short* Kbf = Wbf + (size_t)EMBED * EMBED;                     // 4 MB
    short* Vbf = Kbf + (size_t)BATCH * HEADS * NCHUNK * 4096;     // 4 MB
    float* vsum_part = (float*)(Vbf + (size_t)BATCH * HEADS * NCHUNK * 4096);
    float* gnum_part = vsum_part + (size_t)BATCH * NCHUNK * EMBED;
    float* gden_part = gnum_part + (size_t)BATCH * HEADS * NCHUNK * HDIM;
    float* nval_part = gden_part + (size_t)BATCH * HEADS * NCHUNK;

    prepass<<<dim3(NCHUNK + 4, HEADS, BATCH), 256, 0, stream>>>(
        query, keys, values, maskp, fc_w, Kbf, Vbf, Wbf,
        gnum_part, gden_part, vsum_part, nval_part);
    windowed_attn_v7<<<dim3(NCHUNK, HEADS, BATCH), 256, 0, stream>>>(
        query, keys, values, maskp, Kbf, Vbf,
        gnum_part, gden_part, vsum_part, nval_part, Abf);
    fc_gemm_v4<<<dim3(BATCH * NCHUNK, EMBED / 64), 256, 0, stream>>>(
        Abf, Wbf, fc_b, out);
}

// Round 10
// 31.730 us; speedup vs baseline: 7.7806x; 1.1002x over previous
//
#include <hip/hip_runtime.h>
#include <math.h>

#define EMBED 512
#define HEADS 8
#define HDIM 64
#define SLEN 2048
#define BATCH 2
#define HALFW 128
#define NCHUNK 32
#define INV_SCALE 0.044194173824159216f  // 1/sqrt(512)

typedef short bf16x8 __attribute__((ext_vector_type(8)));
typedef short s16x4  __attribute__((ext_vector_type(4)));
typedef float f32x4  __attribute__((ext_vector_type(4)));

#define MFMA16(a, b, c) __builtin_amdgcn_mfma_f32_16x16x32_bf16(a, b, c, 0, 0, 0)

__device__ __forceinline__ short f2bf(float x) {
    union { float f; unsigned u; } v; v.f = x;
    unsigned r = v.u + 0x7FFFu + ((v.u >> 16) & 1u);  // RNE
    return (short)(r >> 16);
}

// Blocked-frag layout for a 64x64 bf16 tile (global AND LDS), XOR-swizzled:
// 16B fragment (row, seg) at short index ((seg*64) + (row^seg)) * 8.
// Frag reads & staging writes bank-conflict-free (R2-R9: SQ_LDS_BANK_CONFLICT=0).
__device__ __forceinline__ int lidx(int row, int seg) {
    return (((seg << 6) + (row ^ seg)) << 3);
}

// async global->LDS, 16B per lane. dest: wave-uniform base, HW adds lane*16.
__device__ __forceinline__ void gll16(const short* g, short* l) {
    __builtin_amdgcn_global_load_lds(
        (const __attribute__((address_space(1))) unsigned int*)g,
        (__attribute__((address_space(3))) unsigned int*)l, 16, 0, 0);
}

// identity-copy two 8KB frag tiles (layout preserved: dest off == src off)
__device__ __forceinline__ void stage_chunk(const short* s0, const short* s1,
                                            short* d0, short* d1, int t) {
    int off = t * 8;              // shorts
    int wb  = (t >> 6) * 512;     // wave-uniform LDS base (shorts)
    gll16(s0 + off,        d0 + wb);
    gll16(s0 + 2048 + off, d0 + 2048 + wb);
    gll16(s1 + off,        d1 + wb);
    gll16(s1 + 2048 + off, d1 + 2048 + wb);
}

// ---------------------------------------------------------------------------
// Kernel 1: prepass. grid 576 (1D, XCD-matched placement), 256 thr.
// dispatch d -> XCD d%8 (HW round-robin heuristic). XCD x processes the two
// (h,b) slabs {2x, 2x+1} that windowed will read on the SAME XCD.
// ---------------------------------------------------------------------------
__global__ __launch_bounds__(256) void prepass(
    const float* __restrict__ q, const float* __restrict__ k,
    const float* __restrict__ v, const int* __restrict__ mask,
    const float* __restrict__ fcw,
    short* __restrict__ Kbf, short* __restrict__ Vbf, short* __restrict__ Wbf,
    float* __restrict__ gnum_part, float* __restrict__ gden_part,
    float* __restrict__ vsum_part, float* __restrict__ nval_part) {
    int d = blockIdx.x;
    int x = d & 7, i = d >> 3;            // 72 works per XCD
    int hb8 = x * 2 + (i >= 36);          // 0..15  (= h + 8*b)
    int c   = (i >= 36) ? (i - 36) : i;   // 0..35
    int h = hb8 & 7, b = hb8 >> 3;
    int t = threadIdx.x, w = t >> 6, l = t & 63;

    if (c >= NCHUNK) {            // ---- fc_w tile (nb, kt=h) -> Wbf frags ----
        int nb = b * 4 + (c - NCHUNK);
        size_t base = (size_t)(nb * 8 + h) * 4096;
        #pragma unroll
        for (int p = 0; p < 4; ++p) {
            int idx = p * 256 + t, row = idx >> 4, kg = idx & 15;
            float4 f = *(const float4*)(fcw + (size_t)(nb * 64 + row) * EMBED + h * 64 + kg * 4);
            s16x4 o;
            o[0] = f2bf(f.x); o[1] = f2bf(f.y); o[2] = f2bf(f.z); o[3] = f2bf(f.w);
            *(s16x4*)&Wbf[base + lidx(row, kg >> 1) + (kg & 1) * 4] = o;
        }
        return;
    }

    int j0 = c * 64;
    __shared__ float q0s[HDIM];
    __shared__ float wls[64];
    __shared__ int   m_s[64];
    __shared__ float vbuf[64][68];
    __shared__ float red[4][HDIM];
    __shared__ float redv[4][HDIM];

    if (t < 64) {
        q0s[t] = q[(size_t)b * SLEN * EMBED + h * HDIM + t];
        m_s[t] = mask[b * SLEN + j0 + t];
    }
    __syncthreads();

    size_t fragbase = ((size_t)(b * HEADS + h) * NCHUNK + c) * 4096;

    #pragma unroll
    for (int p = 0; p < 4; ++p) {
        int idx = p * 256 + t, row = idx >> 4, kg = idx & 15;
        float4 f = *(const float4*)(k + ((size_t)b * SLEN + j0 + row) * EMBED + h * HDIM + kg * 4);
        float dot = q0s[kg*4+0]*f.x + q0s[kg*4+1]*f.y + q0s[kg*4+2]*f.z + q0s[kg*4+3]*f.w;
        dot += __shfl_xor(dot, 1, 64);
        dot += __shfl_xor(dot, 2, 64);
        dot += __shfl_xor(dot, 4, 64);
        dot += __shfl_xor(dot, 8, 64);
        if ((t & 15) == 0) wls[row] = __expf(dot * INV_SCALE);
        if (!m_s[row]) f = make_float4(0.f, 0.f, 0.f, 0.f);
        s16x4 o;
        o[0] = f2bf(f.x); o[1] = f2bf(f.y); o[2] = f2bf(f.z); o[3] = f2bf(f.w);
        *(s16x4*)&Kbf[fragbase + lidx(row, kg >> 1) + (kg & 1) * 4] = o;
    }

    #pragma unroll
    for (int p = 0; p < 4; ++p) {
        int idx = p * 256 + t, row = idx >> 4, kg = idx & 15;
        float4 f = *(const float4*)(v + ((size_t)b * SLEN + j0 + row) * EMBED + h * HDIM + kg * 4);
        *(float4*)&vbuf[row][kg * 4] = f;
    }
    __syncthreads();

    float num = 0.f, vs = 0.f;
    #pragma unroll
    for (int jj = 0; jj < 16; ++jj) {
        int jl = w * 16 + jj;
        float vv = vbuf[jl][l];
        num += wls[jl] * vv;
        if (m_s[jl]) vs += vv;
    }
    red[w][l] = num;
    redv[w][l] = vs;

    #pragma unroll
    for (int s = 0; s < 2; ++s) {
        int jseg = w * 2 + s;
        bf16x8 o;
        #pragma unroll
        for (int e = 0; e < 8; ++e) o[e] = f2bf(vbuf[jseg * 8 + e][l]);
        *(bf16x8*)&Vbf[fragbase + lidx(l, jseg)] = o;
    }
    __syncthreads();

    if (w == 0) {
        gnum_part[((size_t)(b * HEADS + h) * NCHUNK + c) * HDIM + l] =
            red[0][l] + red[1][l] + red[2][l] + red[3][l];
        vsum_part[((size_t)b * NCHUNK + c) * EMBED + h * HDIM + l] =
            redv[0][l] + redv[1][l] + redv[2][l] + redv[3][l];
    } else if (w == 1) {
        float s = wls[l];
        #pragma unroll
        for (int off = 32; off > 0; off >>= 1) s += __shfl_xor(s, off, 64);
        if (l == 0) gden_part[(size_t)(b * HEADS + h) * NCHUNK + c] = s;
    } else if (w == 2 && h == 0) {
        float cc = m_s[l] ? 1.f : 0.f;
        #pragma unroll
        for (int off = 32; off > 0; off >>= 1) cc += __shfl_xor(cc, off, 64);
        if (l == 0) nval_part[b * NCHUNK + c] = cc;
    }
}

// ---------------------------------------------------------------------------
// Kernel 2: windowed attention v8 — 4-buffer K/V, 3-ahead counted vmcnt,
// XCD-chunked work order (XCD x owns heads {2x,2x+1} — same placement as
// prepass wrote them, so stage reads are local-L2).
// ---------------------------------------------------------------------------
__global__ __launch_bounds__(256) void windowed_attn_v8(
    const float* __restrict__ q, const float* __restrict__ k,
    const float* __restrict__ v, const int* __restrict__ mask,
    const short* __restrict__ Kbf, const short* __restrict__ Vbf,
    const float* __restrict__ gnum_part, const float* __restrict__ gden_part,
    const float* __restrict__ vsum_part, const float* __restrict__ nval_part,
    short* __restrict__ Abf) {
    int dsp = blockIdx.x;
    int wid = (dsp & 7) * 64 + (dsp >> 3);   // chunked: XCD x -> wids x*64..+63
    int tile = wid & 31, h = (wid >> 5) & 7, b = wid >> 8;
    int r0 = tile * 64;
    int t = threadIdx.x, w = t >> 6, l = t & 63;
    int lg = l >> 4, lr = l & 15;

    __shared__ __align__(16) short k_s[4][4096];
    __shared__ __align__(16) short v_s[4][4096];
    __shared__ __align__(16) short wT_s[4][16][72];
    __shared__ float rsum[64];
    __shared__ float vred[4][64];
    __shared__ float gred[4][64];
    __shared__ float nv_s, gd_s;

    size_t hb = (size_t)(b * HEADS + h) * NCHUNK;
    int bh = b * HEADS + h;

    int c0 = tile - 2; if (c0 < 0) c0 = 0;
    int c1 = tile + 2; if (c1 > NCHUNK - 1) c1 = NCHUNK - 1;
    // always >= 3 chunks, so prologue stages 3 unconditionally.

    stage_chunk(Kbf + (hb + c0) * 4096, Vbf + (hb + c0) * 4096,
                &k_s[0][0], &v_s[0][0], t);

    // ---- Q frags direct from global (fp32 -> bf16), consumed before loop ----
    const float* qrow = q + ((size_t)b * SLEN + r0 + w * 16 + lr) * EMBED + h * HDIM;
    float4 a0 = *(const float4*)(qrow + lg * 8);
    float4 a1 = *(const float4*)(qrow + lg * 8 + 4);
    float4 a2 = *(const float4*)(qrow + 32 + lg * 8);
    float4 a3 = *(const float4*)(qrow + 32 + lg * 8 + 4);
    bf16x8 qb0, qb1;
    qb0[0] = f2bf(a0.x); qb0[1] = f2bf(a0.y); qb0[2] = f2bf(a0.z); qb0[3] = f2bf(a0.w);
    qb0[4] = f2bf(a1.x); qb0[5] = f2bf(a1.y); qb0[6] = f2bf(a1.z); qb0[7] = f2bf(a1.w);
    qb1[0] = f2bf(a2.x); qb1[1] = f2bf(a2.y); qb1[2] = f2bf(a2.z); qb1[3] = f2bf(a2.w);
    qb1[4] = f2bf(a3.x); qb1[5] = f2bf(a3.y); qb1[6] = f2bf(a3.z); qb1[7] = f2bf(a3.w);

    // ---- reduce prepass partials (uses force their waits before next stage) ----
    {
        float vp = 0.f;
        #pragma unroll
        for (int cc = 0; cc < 8; ++cc)
            vp += vsum_part[((size_t)b * NCHUNK + w * 8 + cc) * EMBED + h * HDIM + l];
        vred[w][l] = vp;
        if (w == 0) {
            float nvv = (l < NCHUNK) ? nval_part[b * NCHUNK + l] : 0.f;
            #pragma unroll
            for (int off = 32; off > 0; off >>= 1) nvv += __shfl_xor(nvv, off, 64);
            if (l == 0) nv_s = nvv;
        }
        if (tile == 0) {
            float gp = 0.f;
            #pragma unroll
            for (int cc = 0; cc < 8; ++cc)
                gp += gnum_part[((size_t)bh * NCHUNK + w * 8 + cc) * HDIM + l];
            gred[w][l] = gp;
            if (w == 1) {
                float gdd = (l < NCHUNK) ? gden_part[(size_t)bh * NCHUNK + l] : 0.f;
                #pragma unroll
                for (int off = 32; off > 0; off >>= 1) gdd += __shfl_xor(gdd, off, 64);
                if (l == 0) gd_s = gdd;
            }
        }
    }

    stage_chunk(Kbf + (hb + c0 + 1) * 4096, Vbf + (hb + c0 + 1) * 4096,
                &k_s[1][0], &v_s[1][0], t);
    stage_chunk(Kbf + (hb + c0 + 2) * 4096, Vbf + (hb + c0 + 2) * 4096,
                &k_s[2][0], &v_s[2][0], t);

    int center = r0 + w * 16 + lr - 1;
    int lo = center - HALFW, hi = center + HALFW;

    f32x4 pv[4];
    #pragma unroll
    for (int dt = 0; dt < 4; ++dt) pv[dt] = (f32x4){0.f, 0.f, 0.f, 0.f};
    float dacc = 0.f;

    int bi = 0;
    for (int c = c0; c <= c1; ++c) {
        // wait for stage(c); keep up to 2 newer stages (8 gll16) in flight
        int rem = c1 - c;
        if (rem >= 2)      { asm volatile("s_waitcnt vmcnt(8)" ::: "memory"); }
        else if (rem == 1) { asm volatile("s_waitcnt vmcnt(4)" ::: "memory"); }
        else               { asm volatile("s_waitcnt vmcnt(0)" ::: "memory"); }
        __syncthreads();

        int jc = c * 64;
        // ---- QK^T (S^T): A = K rows, B = Q ----
        #pragma unroll
        for (int jt = 0; jt < 4; ++jt) {
            bf16x8 ka0 = *(const bf16x8*)&k_s[bi][lidx(jt * 16 + lr, lg)];
            bf16x8 ka1 = *(const bf16x8*)&k_s[bi][lidx(jt * 16 + lr, 4 + lg)];
            f32x4 sT = (f32x4){0.f, 0.f, 0.f, 0.f};
            sT = MFMA16(ka0, qb0, sT);
            sT = MFMA16(ka1, qb1, sT);
            int jbase = jc + jt * 16 + lg * 4;
            s16x4 wq;
            #pragma unroll
            for (int r = 0; r < 4; ++r) {
                int j = jbase + r;
                float wgt = (j >= lo && j <= hi) ? (__expf(sT[r] * INV_SCALE) - 1.f) : 0.f;
                dacc += wgt;
                wq[r] = f2bf(wgt);
            }
            *(s16x4*)&wT_s[w][lr][jt * 16 + lg * 4] = wq;
        }

        // ---- PV: A = w^T strip (wave-private), B = V^T frags ----
        bf16x8 wa0 = *(const bf16x8*)&wT_s[w][lr][lg * 8];
        bf16x8 wa1 = *(const bf16x8*)&wT_s[w][lr][32 + lg * 8];
        #pragma unroll
        for (int dt = 0; dt < 4; ++dt) {
            bf16x8 va0 = *(const bf16x8*)&v_s[bi][lidx(dt * 16 + lr, lg)];
            bf16x8 va1 = *(const bf16x8*)&v_s[bi][lidx(dt * 16 + lr, 4 + lg)];
            pv[dt] = MFMA16(wa0, va0, pv[dt]);
            pv[dt] = MFMA16(wa1, va1, pv[dt]);
        }

        // stage chunk c+3 into buffer (bi+3)&3 = buffer of compute(c-1);
        // safe: all waves passed this iter's barrier after finishing c-1.
        if (c + 3 <= c1) {
            int bn = (bi + 3) & 3;
            stage_chunk(Kbf + (hb + c + 3) * 4096, Vbf + (hb + c + 3) * 4096,
                        &k_s[bn][0], &v_s[bn][0], t);
        }
        bi = (bi + 1) & 3;
    }

    // ---- single-key fixup: row r0, key jx = r0-129 ----
    float wfix = 0.f;
    int jx = r0 - 129;
    if (w == 0 && jx >= 0) {
        float qv = q[((size_t)b * SLEN + r0) * EMBED + h * HDIM + l];
        float kv = k[((size_t)b * SLEN + jx) * EMBED + h * HDIM + l];
        float dd = qv * kv;
        #pragma unroll
        for (int off = 32; off > 0; off >>= 1) dd += __shfl_xor(dd, off, 64);
        if (mask[b * SLEN + jx] != 0) wfix = __expf(dd * INV_SCALE) - 1.f;
        if (lg == 0) {
            #pragma unroll
            for (int dt = 0; dt < 4; ++dt)
                pv[dt][0] += wfix * v[((size_t)b * SLEN + jx) * EMBED + h * HDIM + dt * 16 + lr];
        }
    }

    // ---- row-sum reduce ----
    dacc += __shfl_xor(dacc, 16, 64);
    dacc += __shfl_xor(dacc, 32, 64);
    if (lg == 0) rsum[w * 16 + lr] = dacc + ((w == 0 && lr == 0) ? wfix : 0.f);
    __syncthreads();

    // ---- epilogue: write fc-A frag tile (row 0 from global-attn partials) ----
    float nv = nv_s;
    float invden[4];
    #pragma unroll
    for (int r = 0; r < 4; ++r)
        invden[r] = 1.f / (nv + rsum[w * 16 + lg * 4 + r]);

    short* Atile = Abf + ((size_t)(b * NCHUNK + tile) * 8 + h) * 4096;
    #pragma unroll
    for (int dt = 0; dt < 4; ++dt) {
        int d = dt * 16 + lr;
        float vs = vred[0][d] + vred[1][d] + vred[2][d] + vred[3][d];
        #pragma unroll
        for (int r = 0; r < 4; ++r) {
            int row_local = w * 16 + lg * 4 + r;
            float o;
            if (tile == 0 && row_local == 0)
                o = (gred[0][d] + gred[1][d] + gred[2][d] + gred[3][d]) / gd_s;
            else
                o = (pv[dt][r] + vs) * invden[r];
            Atile[lidx(row_local, d >> 3) + (d & 7)] = f2bf(o);
        }
    }
}

// ---------------------------------------------------------------------------
// Kernel 3: FC GEMM v4 — A-strip staged once (64 KB), W double-buffered with
// counted vmcnt; no drains in the K loop. LDS 80 KB -> 2 blocks/CU.
// ---------------------------------------------------------------------------
__global__ __launch_bounds__(256) void fc_gemm_v4(
    const short* __restrict__ Abf, const short* __restrict__ Wbf,
    const float* __restrict__ bias, float* __restrict__ C) {
    int bm = blockIdx.x;          // 0..63
    int nb = blockIdx.y;          // 0..7
    int t = threadIdx.x, w = t >> 6, l = t & 63;
    int lg = l >> 4, lr = l & 15;
    int wr = w >> 1, wc = w & 1;

    __shared__ __align__(16) short a_s[8][4096];   // full A strip (64 KB)
    __shared__ __align__(16) short w_s[2][4096];   // W dbuf (16 KB)

    int off = t * 8;
    int wb  = (t >> 6) * 512;

    #pragma unroll
    for (int kt = 0; kt < 8; ++kt) {
        const short* as = Abf + (size_t)(bm * 8 + kt) * 4096;
        gll16(as + off,        &a_s[kt][wb]);
        gll16(as + 2048 + off, &a_s[kt][2048 + wb]);
    }
    {
        const short* ws0 = Wbf + (size_t)(nb * 8 + 0) * 4096;
        gll16(ws0 + off,        &w_s[0][wb]);
        gll16(ws0 + 2048 + off, &w_s[0][2048 + wb]);
        const short* ws1 = Wbf + (size_t)(nb * 8 + 1) * 4096;
        gll16(ws1 + off,        &w_s[1][wb]);
        gll16(ws1 + 2048 + off, &w_s[1][2048 + wb]);
    }

    f32x4 acc[2][2];
    #pragma unroll
    for (int mt = 0; mt < 2; ++mt)
        #pragma unroll
        for (int nt = 0; nt < 2; ++nt) acc[mt][nt] = (f32x4){0.f, 0.f, 0.f, 0.f};

    for (int kt = 0; kt < 8; ++kt) {
        if (kt < 7) { asm volatile("s_waitcnt vmcnt(2)" ::: "memory"); }
        else        { asm volatile("s_waitcnt vmcnt(0)" ::: "memory"); }
        __syncthreads();

        bf16x8 af[2][2], bf_[2][2];
        #pragma unroll
        for (int mt = 0; mt < 2; ++mt) {
            af[mt][0] = *(const bf16x8*)&a_s[kt][lidx(wr * 32 + mt * 16 + lr, lg)];
            af[mt][1] = *(const bf16x8*)&a_s[kt][lidx(wr * 32 + mt * 16 + lr, 4 + lg)];
        }
        int wbuf = kt & 1;
        #pragma unroll
        for (int nt = 0; nt < 2; ++nt) {
            bf_[nt][0] = *(const bf16x8*)&w_s[wbuf][lidx(wc * 32 + nt * 16 + lr, lg)];
            bf_[nt][1] = *(const bf16x8*)&w_s[wbuf][lidx(wc * 32 + nt * 16 + lr, 4 + lg)];
        }
        #pragma unroll
        for (int mt = 0; mt < 2; ++mt)
            #pragma unroll
            for (int nt = 0; nt < 2; ++nt) {
                acc[mt][nt] = MFMA16(af[mt][0], bf_[nt][0], acc[mt][nt]);
                acc[mt][nt] = MFMA16(af[mt][1], bf_[nt][1], acc[mt][nt]);
            }

        __syncthreads();   // all waves done reading w_s[wbuf] before restage
        if (kt + 2 <= 7) {
            const short* ws = Wbf + (size_t)(nb * 8 + kt + 2) * 4096;
            gll16(ws + off,        &w_s[wbuf][wb]);
            gll16(ws + 2048 + off, &w_s[wbuf][2048 + wb]);
        }
    }

    #pragma unroll
    for (int mt = 0; mt < 2; ++mt)
        #pragma unroll
        for (int nt = 0; nt < 2; ++nt) {
            int n = nb * 64 + wc * 32 + nt * 16 + lr;
            float bb = bias[n];
            #pragma unroll
            for (int reg = 0; reg < 4; ++reg) {
                int m = bm * 64 + wr * 32 + mt * 16 + lg * 4 + reg;
                C[(size_t)m * 512 + n] = acc[mt][nt][reg] + bb;
            }
        }
}

// ---------------------------------------------------------------------------
extern "C" void kernel_launch(void* const* d_in, const int* in_sizes, int n_in,
                              void* d_out, int out_size, void* d_ws, size_t ws_size,
                              hipStream_t stream) {
    const float* values = (const float*)d_in[0];
    const float* keys   = (const float*)d_in[1];
    const float* query  = (const float*)d_in[2];
    const int*   maskp  = (const int*)d_in[3];
    const float* fc_w   = (const float*)d_in[4];
    const float* fc_b   = (const float*)d_in[5];
    float* out = (float*)d_out;

    short* Abf = (short*)d_ws;                                    // 4 MB
    short* Wbf = Abf + (size_t)BATCH * SLEN * EMBED;              // 512 KB
    short* Kbf = Wbf + (size_t)EMBED * EMBED;                     // 4 MB
    short* Vbf = Kbf + (size_t)BATCH * HEADS * NCHUNK * 4096;     // 4 MB
    float* vsum_part = (float*)(Vbf + (size_t)BATCH * HEADS * NCHUNK * 4096);
    float* gnum_part = vsum_part + (size_t)BATCH * NCHUNK * EMBED;
    float* gden_part = gnum_part + (size_t)BATCH * HEADS * NCHUNK * HDIM;
    float* nval_part = gden_part + (size_t)BATCH * HEADS * NCHUNK;

    prepass<<<dim3(576), 256, 0, stream>>>(
        query, keys, values, maskp, fc_w, Kbf, Vbf, Wbf,
        gnum_part, gden_part, vsum_part, nval_part);
    windowed_attn_v8<<<dim3(512), 256, 0, stream>>>(
        query, keys, values, maskp, Kbf, Vbf,
        gnum_part, gden_part, vsum_part, nval_part, Abf);
    fc_gemm_v4<<<dim3(64, 8), 256, 0, stream>>>(
        Abf, Wbf, fc_b, out);
}

// Round 11
// 30.943 us; speedup vs baseline: 7.9785x; 1.0254x over previous
//
#include <hip/hip_runtime.h>
#include <math.h>

#define EMBED 512
#define HEADS 8
#define HDIM 64
#define SLEN 2048
#define BATCH 2
#define HALFW 128
#define NCHUNK 32
#define INV_SCALE 0.044194173824159216f  // 1/sqrt(512)

typedef short bf16x8 __attribute__((ext_vector_type(8)));
typedef short s16x4  __attribute__((ext_vector_type(4)));
typedef float f32x4  __attribute__((ext_vector_type(4)));

#define MFMA16(a, b, c) __builtin_amdgcn_mfma_f32_16x16x32_bf16(a, b, c, 0, 0, 0)

__device__ __forceinline__ short f2bf(float x) {
    union { float f; unsigned u; } v; v.f = x;
    unsigned r = v.u + 0x7FFFu + ((v.u >> 16) & 1u);  // RNE
    return (short)(r >> 16);
}

// Blocked-frag layout for a 64x64 bf16 tile (global AND LDS), XOR-swizzled:
// 16B fragment (row, seg) at short index ((seg*64) + (row^seg)) * 8.
// Frag reads & staging writes bank-conflict-free (R2-R10: SQ_LDS_BANK_CONFLICT=0).
__device__ __forceinline__ int lidx(int row, int seg) {
    return (((seg << 6) + (row ^ seg)) << 3);
}

// async global->LDS, 16B per lane. dest: wave-uniform base, HW adds lane*16.
__device__ __forceinline__ void gll16(const short* g, short* l) {
    __builtin_amdgcn_global_load_lds(
        (const __attribute__((address_space(1))) unsigned int*)g,
        (__attribute__((address_space(3))) unsigned int*)l, 16, 0, 0);
}

// identity-copy two 8KB frag tiles (layout preserved: dest off == src off)
__device__ __forceinline__ void stage_chunk(const short* s0, const short* s1,
                                            short* d0, short* d1, int t) {
    int off = t * 8;              // shorts
    int wb  = (t >> 6) * 512;     // wave-uniform LDS base (shorts)
    gll16(s0 + off,        d0 + wb);
    gll16(s0 + 2048 + off, d0 + 2048 + wb);
    gll16(s1 + off,        d1 + wb);
    gll16(s1 + 2048 + off, d1 + 2048 + wb);
}

// stage one 8KB tile (2 gll16)
__device__ __forceinline__ void stage_tile(const short* s, short* d, int t) {
    int off = t * 8;
    int wb  = (t >> 6) * 512;
    gll16(s + off,        d + wb);
    gll16(s + 2048 + off, d + 2048 + wb);
}

// ---------------------------------------------------------------------------
// Kernel 1: prepass, HALF-CHUNK granularity (32 key-rows per block).
// grid 1088 1D, XCD-matched: XCD x owns hb8 in {2x,2x+1}; per hb8: 64
// half-chunks + 4 fc_w tiles. ~4.25 blocks/CU (2x TLP vs R10).
// Partials are per-half-chunk (64 slots), unique writer per slot.
// ---------------------------------------------------------------------------
__global__ __launch_bounds__(256) void prepass(
    const float* __restrict__ q, const float* __restrict__ k,
    const float* __restrict__ v, const int* __restrict__ mask,
    const float* __restrict__ fcw,
    short* __restrict__ Kbf, short* __restrict__ Vbf, short* __restrict__ Wbf,
    float* __restrict__ gnum_part, float* __restrict__ gden_part,
    float* __restrict__ vsum_part, float* __restrict__ nval_part) {
    int d = blockIdx.x;
    int x = d & 7, i = d >> 3;            // 136 works per XCD
    int hb8 = x * 2 + (i >= 68);          // 0..15 (= b*8 + h)
    int ii  = (i >= 68) ? (i - 68) : i;   // 0..67
    int h = hb8 & 7, b = hb8 >> 3;
    int t = threadIdx.x, w = t >> 6, l = t & 63;

    if (ii >= 64) {               // ---- fc_w tile -> Wbf frags ----
        int widx = hb8 * 4 + (ii - 64);   // 0..63
        int nb = widx >> 3, kt = widx & 7;
        size_t base = (size_t)(nb * 8 + kt) * 4096;
        #pragma unroll
        for (int p = 0; p < 4; ++p) {
            int idx = p * 256 + t, row = idx >> 4, kg = idx & 15;
            float4 f = *(const float4*)(fcw + (size_t)(nb * 64 + row) * EMBED + kt * 64 + kg * 4);
            s16x4 o;
            o[0] = f2bf(f.x); o[1] = f2bf(f.y); o[2] = f2bf(f.z); o[3] = f2bf(f.w);
            *(s16x4*)&Wbf[base + lidx(row, kg >> 1) + (kg & 1) * 4] = o;
        }
        return;
    }

    int ch  = ii;                 // half-chunk 0..63
    int c   = ch >> 1;            // 64-key chunk
    int rof = (ch & 1) * 32;      // row offset within chunk tile
    int j0  = ch * 32;            // global key start

    __shared__ float q0s[HDIM];
    __shared__ float wls[32];
    __shared__ int   m_s[32];
    __shared__ float vbuf[32][68];
    __shared__ float red[4][HDIM];
    __shared__ float redv[4][HDIM];

    if (t < 64) q0s[t] = q[(size_t)b * SLEN * EMBED + h * HDIM + t];
    else if (t < 96) m_s[t - 64] = mask[b * SLEN + j0 + (t - 64)];
    __syncthreads();

    size_t fragbase = ((size_t)(b * HEADS + h) * NCHUNK + c) * 4096;

    // ---- K half-chunk -> Kbf frags (masked rows zeroed) + row-0 dot ----
    #pragma unroll
    for (int p = 0; p < 2; ++p) {
        int idx = p * 256 + t, row = idx >> 4, kg = idx & 15;   // row 0..31
        float4 f = *(const float4*)(k + ((size_t)b * SLEN + j0 + row) * EMBED + h * HDIM + kg * 4);
        float dot = q0s[kg*4+0]*f.x + q0s[kg*4+1]*f.y + q0s[kg*4+2]*f.z + q0s[kg*4+3]*f.w;
        dot += __shfl_xor(dot, 1, 64);
        dot += __shfl_xor(dot, 2, 64);
        dot += __shfl_xor(dot, 4, 64);
        dot += __shfl_xor(dot, 8, 64);
        if ((t & 15) == 0) wls[row] = __expf(dot * INV_SCALE);
        if (!m_s[row]) f = make_float4(0.f, 0.f, 0.f, 0.f);
        s16x4 o;
        o[0] = f2bf(f.x); o[1] = f2bf(f.y); o[2] = f2bf(f.z); o[3] = f2bf(f.w);
        *(s16x4*)&Kbf[fragbase + lidx(rof + row, kg >> 1) + (kg & 1) * 4] = o;
    }

    // ---- V half-chunk -> LDS (fp32, padded) ----
    #pragma unroll
    for (int p = 0; p < 2; ++p) {
        int idx = p * 256 + t, row = idx >> 4, kg = idx & 15;
        float4 f = *(const float4*)(v + ((size_t)b * SLEN + j0 + row) * EMBED + h * HDIM + kg * 4);
        *(float4*)&vbuf[row][kg * 4] = f;
    }
    __syncthreads();

    // ---- row-0 PV + vsum partials: lane = d, wave w covers 8 j ----
    float num = 0.f, vs = 0.f;
    #pragma unroll
    for (int jj = 0; jj < 8; ++jj) {
        int jl = w * 8 + jj;
        float vv = vbuf[jl][l];
        num += wls[jl] * vv;
        if (m_s[jl]) vs += vv;
    }
    red[w][l] = num;
    redv[w][l] = vs;

    // ---- V -> Vbf transposed frags: wave w -> jseg rof/8 + w ----
    {
        int jseg = (ch & 1) * 4 + w;
        bf16x8 o;
        #pragma unroll
        for (int e = 0; e < 8; ++e) o[e] = f2bf(vbuf[w * 8 + e][l]);
        *(bf16x8*)&Vbf[fragbase + lidx(l, jseg)] = o;
    }
    __syncthreads();

    // ---- deterministic partial writes (unique writer per half-chunk slot) ----
    if (w == 0) {
        gnum_part[((size_t)(b * HEADS + h) * 64 + ch) * HDIM + l] =
            red[0][l] + red[1][l] + red[2][l] + red[3][l];
        vsum_part[((size_t)b * 64 + ch) * EMBED + h * HDIM + l] =
            redv[0][l] + redv[1][l] + redv[2][l] + redv[3][l];
    } else if (w == 1) {
        float s = (l < 32) ? wls[l] : 0.f;
        #pragma unroll
        for (int off = 32; off > 0; off >>= 1) s += __shfl_xor(s, off, 64);
        if (l == 0) gden_part[(size_t)(b * HEADS + h) * 64 + ch] = s;
    } else if (w == 2 && h == 0) {
        float cc = (l < 32 && m_s[l]) ? 1.f : 0.f;
        #pragma unroll
        for (int off = 32; off > 0; off >>= 1) cc += __shfl_xor(cc, off, 64);
        if (l == 0) nval_part[b * 64 + ch] = cc;
    }
}

// ---------------------------------------------------------------------------
// Kernel 2: windowed attention v9 — 4-buffer K/V, 3-ahead counted vmcnt,
// XCD-chunked work order matched to prepass placement. Partial reduction
// widened to 64 half-chunk slots (hidden under first stage).
// ---------------------------------------------------------------------------
__global__ __launch_bounds__(256) void windowed_attn_v9(
    const float* __restrict__ q, const float* __restrict__ k,
    const float* __restrict__ v, const int* __restrict__ mask,
    const short* __restrict__ Kbf, const short* __restrict__ Vbf,
    const float* __restrict__ gnum_part, const float* __restrict__ gden_part,
    const float* __restrict__ vsum_part, const float* __restrict__ nval_part,
    short* __restrict__ Abf) {
    int dsp = blockIdx.x;
    int wid = (dsp & 7) * 64 + (dsp >> 3);   // chunked: XCD x -> wids x*64..+63
    int tile = wid & 31, h = (wid >> 5) & 7, b = wid >> 8;
    int r0 = tile * 64;
    int t = threadIdx.x, w = t >> 6, l = t & 63;
    int lg = l >> 4, lr = l & 15;

    __shared__ __align__(16) short k_s[4][4096];
    __shared__ __align__(16) short v_s[4][4096];
    __shared__ __align__(16) short wT_s[4][16][72];
    __shared__ float rsum[64];
    __shared__ float vred[4][64];
    __shared__ float gred[4][64];
    __shared__ float nv_s, gd_s;

    size_t hb = (size_t)(b * HEADS + h) * NCHUNK;
    int bh = b * HEADS + h;

    int c0 = tile - 2; if (c0 < 0) c0 = 0;
    int c1 = tile + 2; if (c1 > NCHUNK - 1) c1 = NCHUNK - 1;

    stage_chunk(Kbf + (hb + c0) * 4096, Vbf + (hb + c0) * 4096,
                &k_s[0][0], &v_s[0][0], t);

    // ---- Q frags direct from global (fp32 -> bf16), consumed before loop ----
    const float* qrow = q + ((size_t)b * SLEN + r0 + w * 16 + lr) * EMBED + h * HDIM;
    float4 a0 = *(const float4*)(qrow + lg * 8);
    float4 a1 = *(const float4*)(qrow + lg * 8 + 4);
    float4 a2 = *(const float4*)(qrow + 32 + lg * 8);
    float4 a3 = *(const float4*)(qrow + 32 + lg * 8 + 4);
    bf16x8 qb0, qb1;
    qb0[0] = f2bf(a0.x); qb0[1] = f2bf(a0.y); qb0[2] = f2bf(a0.z); qb0[3] = f2bf(a0.w);
    qb0[4] = f2bf(a1.x); qb0[5] = f2bf(a1.y); qb0[6] = f2bf(a1.z); qb0[7] = f2bf(a1.w);
    qb1[0] = f2bf(a2.x); qb1[1] = f2bf(a2.y); qb1[2] = f2bf(a2.z); qb1[3] = f2bf(a2.w);
    qb1[4] = f2bf(a3.x); qb1[5] = f2bf(a3.y); qb1[6] = f2bf(a3.z); qb1[7] = f2bf(a3.w);

    // ---- reduce prepass half-chunk partials (hidden under stage(c0)) ----
    {
        float vp = 0.f;
        #pragma unroll
        for (int cc = 0; cc < 16; ++cc)
            vp += vsum_part[((size_t)b * 64 + w * 16 + cc) * EMBED + h * HDIM + l];
        vred[w][l] = vp;
        if (w == 0) {
            float nvv = nval_part[b * 64 + l];
            #pragma unroll
            for (int off = 32; off > 0; off >>= 1) nvv += __shfl_xor(nvv, off, 64);
            if (l == 0) nv_s = nvv;
        }
        if (tile == 0) {
            float gp = 0.f;
            #pragma unroll
            for (int cc = 0; cc < 16; ++cc)
                gp += gnum_part[((size_t)bh * 64 + w * 16 + cc) * HDIM + l];
            gred[w][l] = gp;
            if (w == 1) {
                float gdd = gden_part[(size_t)bh * 64 + l];
                #pragma unroll
                for (int off = 32; off > 0; off >>= 1) gdd += __shfl_xor(gdd, off, 64);
                if (l == 0) gd_s = gdd;
            }
        }
    }

    stage_chunk(Kbf + (hb + c0 + 1) * 4096, Vbf + (hb + c0 + 1) * 4096,
                &k_s[1][0], &v_s[1][0], t);
    stage_chunk(Kbf + (hb + c0 + 2) * 4096, Vbf + (hb + c0 + 2) * 4096,
                &k_s[2][0], &v_s[2][0], t);

    int center = r0 + w * 16 + lr - 1;
    int lo = center - HALFW, hi = center + HALFW;

    f32x4 pv[4];
    #pragma unroll
    for (int dt = 0; dt < 4; ++dt) pv[dt] = (f32x4){0.f, 0.f, 0.f, 0.f};
    float dacc = 0.f;

    int bi = 0;
    for (int c = c0; c <= c1; ++c) {
        // wait for stage(c); keep up to 2 newer stages (8 gll16) in flight
        int rem = c1 - c;
        if (rem >= 2)      { asm volatile("s_waitcnt vmcnt(8)" ::: "memory"); }
        else if (rem == 1) { asm volatile("s_waitcnt vmcnt(4)" ::: "memory"); }
        else               { asm volatile("s_waitcnt vmcnt(0)" ::: "memory"); }
        __syncthreads();

        int jc = c * 64;
        // ---- QK^T (S^T): A = K rows, B = Q ----
        #pragma unroll
        for (int jt = 0; jt < 4; ++jt) {
            bf16x8 ka0 = *(const bf16x8*)&k_s[bi][lidx(jt * 16 + lr, lg)];
            bf16x8 ka1 = *(const bf16x8*)&k_s[bi][lidx(jt * 16 + lr, 4 + lg)];
            f32x4 sT = (f32x4){0.f, 0.f, 0.f, 0.f};
            sT = MFMA16(ka0, qb0, sT);
            sT = MFMA16(ka1, qb1, sT);
            int jbase = jc + jt * 16 + lg * 4;
            s16x4 wq;
            #pragma unroll
            for (int r = 0; r < 4; ++r) {
                int j = jbase + r;
                float wgt = (j >= lo && j <= hi) ? (__expf(sT[r] * INV_SCALE) - 1.f) : 0.f;
                dacc += wgt;
                wq[r] = f2bf(wgt);
            }
            *(s16x4*)&wT_s[w][lr][jt * 16 + lg * 4] = wq;
        }

        // ---- PV: A = w^T strip (wave-private), B = V^T frags ----
        bf16x8 wa0 = *(const bf16x8*)&wT_s[w][lr][lg * 8];
        bf16x8 wa1 = *(const bf16x8*)&wT_s[w][lr][32 + lg * 8];
        #pragma unroll
        for (int dt = 0; dt < 4; ++dt) {
            bf16x8 va0 = *(const bf16x8*)&v_s[bi][lidx(dt * 16 + lr, lg)];
            bf16x8 va1 = *(const bf16x8*)&v_s[bi][lidx(dt * 16 + lr, 4 + lg)];
            pv[dt] = MFMA16(wa0, va0, pv[dt]);
            pv[dt] = MFMA16(wa1, va1, pv[dt]);
        }

        // stage chunk c+3 into buffer (bi+3)&3 = buffer of compute(c-1);
        // safe: all waves passed this iter's barrier after finishing c-1.
        if (c + 3 <= c1) {
            int bn = (bi + 3) & 3;
            stage_chunk(Kbf + (hb + c + 3) * 4096, Vbf + (hb + c + 3) * 4096,
                        &k_s[bn][0], &v_s[bn][0], t);
        }
        bi = (bi + 1) & 3;
    }

    // ---- single-key fixup: row r0, key jx = r0-129 ----
    float wfix = 0.f;
    int jx = r0 - 129;
    if (w == 0 && jx >= 0) {
        float qv = q[((size_t)b * SLEN + r0) * EMBED + h * HDIM + l];
        float kv = k[((size_t)b * SLEN + jx) * EMBED + h * HDIM + l];
        float dd = qv * kv;
        #pragma unroll
        for (int off = 32; off > 0; off >>= 1) dd += __shfl_xor(dd, off, 64);
        if (mask[b * SLEN + jx] != 0) wfix = __expf(dd * INV_SCALE) - 1.f;
        if (lg == 0) {
            #pragma unroll
            for (int dt = 0; dt < 4; ++dt)
                pv[dt][0] += wfix * v[((size_t)b * SLEN + jx) * EMBED + h * HDIM + dt * 16 + lr];
        }
    }

    // ---- row-sum reduce ----
    dacc += __shfl_xor(dacc, 16, 64);
    dacc += __shfl_xor(dacc, 32, 64);
    if (lg == 0) rsum[w * 16 + lr] = dacc + ((w == 0 && lr == 0) ? wfix : 0.f);
    __syncthreads();

    // ---- epilogue: write fc-A frag tile (row 0 from global-attn partials) ----
    float nv = nv_s;
    float invden[4];
    #pragma unroll
    for (int r = 0; r < 4; ++r)
        invden[r] = 1.f / (nv + rsum[w * 16 + lg * 4 + r]);

    short* Atile = Abf + ((size_t)(b * NCHUNK + tile) * 8 + h) * 4096;
    #pragma unroll
    for (int dt = 0; dt < 4; ++dt) {
        int d = dt * 16 + lr;
        float vs = vred[0][d] + vred[1][d] + vred[2][d] + vred[3][d];
        #pragma unroll
        for (int r = 0; r < 4; ++r) {
            int row_local = w * 16 + lg * 4 + r;
            float o;
            if (tile == 0 && row_local == 0)
                o = (gred[0][d] + gred[1][d] + gred[2][d] + gred[3][d]) / gd_s;
            else
                o = (pv[dt][r] + vs) * invden[r];
            Atile[lidx(row_local, d >> 3) + (d & 7)] = f2bf(o);
        }
    }
}

// ---------------------------------------------------------------------------
// Kernel 3: FC GEMM v5 — A-strip staged once, prologue reordered so iter 0
// waits only A0+W0 (4 loads) instead of the whole strip; counted vmcnt.
// FIFO (in-order): A0(0-1) W0(2-3) W1(4-5) A1(6-7) .. A7(18-19), then W(kt+2)
// appended at end of iter kt. Waits: kt0->16, kt1->14, kt<7->2, kt7->0.
// ---------------------------------------------------------------------------
__global__ __launch_bounds__(256) void fc_gemm_v5(
    const short* __restrict__ Abf, const short* __restrict__ Wbf,
    const float* __restrict__ bias, float* __restrict__ C) {
    int bm = blockIdx.x;          // 0..63
    int nb = blockIdx.y;          // 0..7
    int t = threadIdx.x, w = t >> 6, l = t & 63;
    int lg = l >> 4, lr = l & 15;
    int wr = w >> 1, wc = w & 1;

    __shared__ __align__(16) short a_s[8][4096];   // full A strip (64 KB)
    __shared__ __align__(16) short w_s[2][4096];   // W dbuf (16 KB)

    // prologue: A0, W0, W1, A1..A7
    stage_tile(Abf + (size_t)(bm * 8 + 0) * 4096, &a_s[0][0], t);
    stage_tile(Wbf + (size_t)(nb * 8 + 0) * 4096, &w_s[0][0], t);
    stage_tile(Wbf + (size_t)(nb * 8 + 1) * 4096, &w_s[1][0], t);
    #pragma unroll
    for (int kt = 1; kt < 8; ++kt)
        stage_tile(Abf + (size_t)(bm * 8 + kt) * 4096, &a_s[kt][0], t);

    f32x4 acc[2][2];
    #pragma unroll
    for (int mt = 0; mt < 2; ++mt)
        #pragma unroll
        for (int nt = 0; nt < 2; ++nt) acc[mt][nt] = (f32x4){0.f, 0.f, 0.f, 0.f};

    for (int kt = 0; kt < 8; ++kt) {
        if (kt == 0)      { asm volatile("s_waitcnt vmcnt(16)" ::: "memory"); }
        else if (kt == 1) { asm volatile("s_waitcnt vmcnt(14)" ::: "memory"); }
        else if (kt < 7)  { asm volatile("s_waitcnt vmcnt(2)"  ::: "memory"); }
        else              { asm volatile("s_waitcnt vmcnt(0)"  ::: "memory"); }
        __syncthreads();

        bf16x8 af[2][2], bf_[2][2];
        #pragma unroll
        for (int mt = 0; mt < 2; ++mt) {
            af[mt][0] = *(const bf16x8*)&a_s[kt][lidx(wr * 32 + mt * 16 + lr, lg)];
            af[mt][1] = *(const bf16x8*)&a_s[kt][lidx(wr * 32 + mt * 16 + lr, 4 + lg)];
        }
        int wbuf = kt & 1;
        #pragma unroll
        for (int nt = 0; nt < 2; ++nt) {
            bf_[nt][0] = *(const bf16x8*)&w_s[wbuf][lidx(wc * 32 + nt * 16 + lr, lg)];
            bf_[nt][1] = *(const bf16x8*)&w_s[wbuf][lidx(wc * 32 + nt * 16 + lr, 4 + lg)];
        }
        #pragma unroll
        for (int mt = 0; mt < 2; ++mt)
            #pragma unroll
            for (int nt = 0; nt < 2; ++nt) {
                acc[mt][nt] = MFMA16(af[mt][0], bf_[nt][0], acc[mt][nt]);
                acc[mt][nt] = MFMA16(af[mt][1], bf_[nt][1], acc[mt][nt]);
            }

        __syncthreads();   // all waves done reading w_s[wbuf] before restage
        if (kt + 2 <= 7)
            stage_tile(Wbf + (size_t)(nb * 8 + kt + 2) * 4096, &w_s[wbuf][0], t);
    }

    #pragma unroll
    for (int mt = 0; mt < 2; ++mt)
        #pragma unroll
        for (int nt = 0; nt < 2; ++nt) {
            int n = nb * 64 + wc * 32 + nt * 16 + lr;
            float bb = bias[n];
            #pragma unroll
            for (int reg = 0; reg < 4; ++reg) {
                int m = bm * 64 + wr * 32 + mt * 16 + lg * 4 + reg;
                C[(size_t)m * 512 + n] = acc[mt][nt][reg] + bb;
            }
        }
}

// ---------------------------------------------------------------------------
extern "C" void kernel_launch(void* const* d_in, const int* in_sizes, int n_in,
                              void* d_out, int out_size, void* d_ws, size_t ws_size,
                              hipStream_t stream) {
    const float* values = (const float*)d_in[0];
    const float* keys   = (const float*)d_in[1];
    const float* query  = (const float*)d_in[2];
    const int*   maskp  = (const int*)d_in[3];
    const float* fc_w   = (const float*)d_in[4];
    const float* fc_b   = (const float*)d_in[5];
    float* out = (float*)d_out;

    short* Abf = (short*)d_ws;                                    // 4 MB
    short* Wbf = Abf + (size_t)BATCH * SLEN * EMBED;              // 512 KB
    short* Kbf = Wbf + (size_t)EMBED * EMBED;                     // 4 MB
    short* Vbf = Kbf + (size_t)BATCH * HEADS * NCHUNK * 4096;     // 4 MB
    float* vsum_part = (float*)(Vbf + (size_t)BATCH * HEADS * NCHUNK * 4096);
    float* gnum_part = vsum_part + (size_t)BATCH * 64 * EMBED;
    float* gden_part = gnum_part + (size_t)BATCH * HEADS * 64 * HDIM;
    float* nval_part = gden_part + (size_t)BATCH * HEADS * 64;

    prepass<<<dim3(1088), 256, 0, stream>>>(
        query, keys, values, maskp, fc_w, Kbf, Vbf, Wbf,
        gnum_part, gden_part, vsum_part, nval_part);
    windowed_attn_v9<<<dim3(512), 256, 0, stream>>>(
        query, keys, values, maskp, Kbf, Vbf,
        gnum_part, gden_part, vsum_part, nval_part, Abf);
    fc_gemm_v5<<<dim3(64, 8), 256, 0, stream>>>(
        Abf, Wbf, fc_b, out);
}